// Round 9
// baseline (710.547 us; speedup 1.0000x reference)
//
#include <hip/hip_runtime.h>

#define NB 8
#define NN 10000
#define NE 320000
#define NF 128
#define NH 128
#define RNG 32            // node ranges per graph
#define RS 313            // ceil(NN/RNG)
#define CAP 16384         // LDS bucket capacity (ints); mean fill ~10016

// ---------------- ws layout (float/int indices into ws) ----------------
// [0,        80000)    dinv    (NB*NN f32)
// [80000,   160000)    deg     (NB*NN i32)
// [160000,  160016)    flag    (i32 edge-dtype detect)
// [160016, 1440016)    mask    (NN*NH f32: 0.0 or 2.0)
// [1440016, 1520024)   offs    (NB*(NN+1) i32) CSR offsets per graph
// [1520024, 1600024)   cursor  (NB*NN i32, legacy slot)
// [1600024, 4160024)   csr     (NB*NE i32) source rows bucketed by dst
// [4160024, 14400024)  y = (X@W)*dinv[row]  (NB*NN*NH f32)

__device__ __forceinline__ int load_edge(const int* ei, size_t idx, int is64) {
    if (is64) return (int)(((const long long*)ei)[idx]);
    return ei[idx];
}

__global__ void detect_kernel(const int* __restrict__ ei, int* __restrict__ flag) {
    __shared__ int s;
    if (threadIdx.x == 0) s = 1;
    __syncthreads();
    int bad = 0;
    for (int q = threadIdx.x; q < 1024; q += 256)
        if (ei[2 * q + 1] != 0) bad = 1;
    if (bad) atomicAnd(&s, 0);
    __syncthreads();
    if (threadIdx.x == 0) *flag = s;   // 1 => int64 layout
}

// JAX threefry2x32, partitionable path: counter i -> (hi=0, lo=i), key (0,42),
// out = x0 ^ x1; keep <=> MSB==0; scale 2.0 (keep) else 0.0.
__global__ void mask_kernel(float* __restrict__ mask) {
    const unsigned TOT = NN * NH;
    unsigned i = blockIdx.x * 256 + threadIdx.x;
    if (i >= TOT) return;
    const unsigned ks0 = 0u, ks1 = 42u, ks2 = 0x1BD11BDAu ^ 0u ^ 42u;
    unsigned x0 = 0u + ks0;
    unsigned x1 = i + ks1;
#define TFR(r) { x0 += x1; x1 = (x1 << (r)) | (x1 >> (32 - (r))); x1 ^= x0; }
    TFR(13) TFR(15) TFR(26) TFR(6)
    x0 += ks1; x1 += ks2 + 1u;
    TFR(17) TFR(29) TFR(16) TFR(24)
    x0 += ks2; x1 += ks0 + 2u;
    TFR(13) TFR(15) TFR(26) TFR(6)
    x0 += ks0; x1 += ks1 + 3u;
    TFR(17) TFR(29) TFR(16) TFR(24)
    x0 += ks1; x1 += ks2 + 4u;
    TFR(13) TFR(15) TFR(26) TFR(6)
    x0 += ks2; x1 += ks0 + 5u;
#undef TFR
    unsigned bits = x0 ^ x1;
    mask[i] = (bits & 0x80000000u) ? 0.0f : 2.0f;
}

// Pass A: per-(graph,range) histogram in LDS, coalesced deg writes.
// Replaces global-atomic deg_kernel. blockIdx&7 = graph (XCD-local: the 32
// workgroups of a graph rescan its 1.28MB col slice from their XCD's L2).
__global__ __launch_bounds__(512) void hist_kernel(const int* __restrict__ ei,
                                                   const int* __restrict__ flag,
                                                   int* __restrict__ deg) {
    int b = blockIdx.x & 7;
    int r = blockIdx.x >> 3;
    int n0 = r * RS;
    int n1 = n0 + RS; if (n1 > NN) n1 = NN;
    __shared__ int cnt[RS];
    for (int i = threadIdx.x; i < RS; i += 512) cnt[i] = 0;
    __syncthreads();
    int is64 = *flag;
    const size_t cbase = (size_t)b * 2 * NE + NE;
    for (int e = threadIdx.x; e < NE; e += 512) {
        int col = load_edge(ei, cbase + e, is64);
        if (col >= n0 && col < n1) atomicAdd(&cnt[col - n0], 1);
    }
    __syncthreads();
    for (int i = threadIdx.x; n0 + i < n1; i += 512) deg[b * NN + n0 + i] = cnt[i];
}

__global__ __launch_bounds__(256) void dinv_kernel(const int* __restrict__ deg,
                                                   float* __restrict__ dinv) {
    int i = blockIdx.x * 256 + threadIdx.x;
    if (i >= NB * NN) return;
    dinv[i] = 1.0f / sqrtf((float)(deg[i] + 1));  // +1 self-loop
}

// Exclusive prefix scan of deg per graph -> offs. 1 block/graph.
__global__ __launch_bounds__(1024) void scan_kernel(const int* __restrict__ deg,
                                                    int* __restrict__ offs) {
    int b = blockIdx.x;
    __shared__ int s[1024];
    int t = threadIdx.x;
    int carry = 0;
    for (int c0 = 0; c0 < NN; c0 += 1024) {
        int i = c0 + t;
        int v = (i < NN) ? deg[b * NN + i] : 0;
        s[t] = v;
        __syncthreads();
        int x = v;
        for (int off = 1; off < 1024; off <<= 1) {
            int add = (t >= off) ? s[t - off] : 0;
            __syncthreads();
            x += add;
            s[t] = x;
            __syncthreads();
        }
        int tot = s[1023];
        if (i < NN) offs[b * (NN + 1) + i] = carry + x - v;   // exclusive
        carry += tot;
        __syncthreads();
    }
    if (t == 0) offs[b * (NN + 1) + NN] = carry;
}

// Pass B: per-(graph,range) bucket fill staged in LDS, then coalesced copy-out.
// Fixes the r4-r7 fill problem: scattered dword stores write through at
// partial-line granularity (measured; atomics/warming don't help) — so stage
// the whole contiguous csr segment in LDS and write it out sequentially.
__global__ __launch_bounds__(512) void fill2_kernel(const int* __restrict__ ei,
                                                    const int* __restrict__ flag,
                                                    const int* __restrict__ offs,
                                                    int* __restrict__ csr) {
    int b = blockIdx.x & 7;
    int r = blockIdx.x >> 3;
    int n0 = r * RS;
    int n1 = n0 + RS; if (n1 > NN) n1 = NN;
    __shared__ int cur[RS];
    __shared__ int buf[CAP];
    const int* ob = offs + b * (NN + 1);
    int s0 = ob[n0], s1 = ob[n1];
    for (int i = threadIdx.x; n0 + i < n1; i += 512) cur[i] = ob[n0 + i] - s0;
    __syncthreads();
    int is64 = *flag;
    size_t base = (size_t)b * 2 * NE;
    int* gcsr = csr + (size_t)b * NE + s0;
    for (int e = threadIdx.x; e < NE; e += 512) {
        int col = load_edge(ei, base + NE + e, is64);
        int row = load_edge(ei, base + e, is64);
        if (col >= n0 && col < n1) {
            int pos = atomicAdd(&cur[col - n0], 1);
            if (pos < CAP) buf[pos] = row;
            else gcsr[pos] = row;              // overflow fallback (statistically never)
        }
    }
    __syncthreads();
    int total = s1 - s0;
    int lim = total < CAP ? total : CAP;
    for (int i = threadIdx.x; i < lim; i += 512) gcsr[i] = buf[i];
}

// y = (X @ W) * dinv[row].  blockIdx.x&7 = graph (XCD-local), >>3 = row block.
__global__ __launch_bounds__(256) void gemm_scale(const float* __restrict__ X,
                                                  const float* __restrict__ Wm,
                                                  const float* __restrict__ dinv,
                                                  float* __restrict__ y) {
    __shared__ float Xs[64][32];
    __shared__ float Ws[32][128];
    int b = blockIdx.x & 7;
    int row0 = (blockIdx.x >> 3) * 64;
    int t = threadIdx.x;
    int cg = t & 31;
    int rg = t >> 5;
    float acc[8][4] = {};
    const float* Xb = X + (size_t)b * NN * NF;

    for (int k0 = 0; k0 < NF; k0 += 32) {
        for (int q = t; q < 512; q += 256) {
            int r = q >> 3, c4 = q & 7;
            int gr = row0 + r;
            float4 v = make_float4(0.f, 0.f, 0.f, 0.f);
            if (gr < NN) v = *(const float4*)(Xb + (size_t)gr * NF + k0 + c4 * 4);
            *(float4*)&Xs[r][c4 * 4] = v;
        }
        for (int q = t; q < 1024; q += 256) {
            float4 v = *(const float4*)(Wm + k0 * NH + q * 4);
            *(float4*)(&Ws[0][0] + q * 4) = v;
        }
        __syncthreads();
#pragma unroll
        for (int kc = 0; kc < 32; kc += 4) {
            float4 xv[8];
#pragma unroll
            for (int i = 0; i < 8; ++i) xv[i] = *(const float4*)&Xs[rg * 8 + i][kc];
#pragma unroll
            for (int j = 0; j < 4; ++j) {
                float4 w = *(const float4*)&Ws[kc + j][cg * 4];
#pragma unroll
                for (int i = 0; i < 8; ++i) {
                    float xsv = (j == 0) ? xv[i].x : (j == 1) ? xv[i].y
                              : (j == 2) ? xv[i].z : xv[i].w;
                    acc[i][0] = fmaf(xsv, w.x, acc[i][0]);
                    acc[i][1] = fmaf(xsv, w.y, acc[i][1]);
                    acc[i][2] = fmaf(xsv, w.z, acc[i][2]);
                    acc[i][3] = fmaf(xsv, w.w, acc[i][3]);
                }
            }
        }
        __syncthreads();
    }
#pragma unroll
    for (int i = 0; i < 8; ++i) {
        int gr = row0 + rg * 8 + i;
        if (gr >= NN) continue;
        float d = dinv[b * NN + gr];
        float4 v = make_float4(acc[i][0] * d, acc[i][1] * d, acc[i][2] * d, acc[i][3] * d);
        *(float4*)(y + ((size_t)b * NN + gr) * NH + cg * 4) = v;
    }
}

__device__ __forceinline__ int chunk_load(const int* __restrict__ csrb,
                                          int base, int o1, int lane) {
    if (base >= o1) return 0;
    int m = o1 - base; if (m > 64) m = 64;
    return (lane < m) ? csrb[base + lane] : 0;
}

// Gather-reduce over one 64-feature half. One wave per TWO nodes (idx, idx+5000):
// two independent csr/y load streams per wave overlap their L2 latencies.
// blockIdx&7 = graph -> per-(graph,half) working set 2.56MB resident in XCD L2.
template<int LAYER>
__global__ __launch_bounds__(256) void aggregate_half(const float* __restrict__ y,
                                                      const int* __restrict__ offs,
                                                      const int* __restrict__ csr,
                                                      const float* __restrict__ dinv,
                                                      const float* __restrict__ bias,
                                                      const float* __restrict__ mask,
                                                      float* __restrict__ out,
                                                      int half) {
    int b = blockIdx.x & 7;
    int w = threadIdx.x >> 6;
    int idx = (blockIdx.x >> 3) * 4 + w;     // [0, 5000)
    int n0 = idx, n1 = idx + 5000;
    int lane = threadIdx.x & 63;
    int sub = lane >> 4;
    int f4 = (lane & 15) * 4 + half * 64;
    const float* yb = y + (size_t)b * NN * NH;

    float4 acc0 = make_float4(0.f, 0.f, 0.f, 0.f);
    float4 acc1 = make_float4(0.f, 0.f, 0.f, 0.f);
    if (sub == 0) {
        acc0 = *(const float4*)(yb + (size_t)n0 * NH + f4);
        acc1 = *(const float4*)(yb + (size_t)n1 * NH + f4);
    }

    const int* ob = offs + b * (NN + 1);
    int o0a = ob[n0], o1a = ob[n0 + 1];
    int o0b = ob[n1], o1b = ob[n1 + 1];
    const int* csrb = csr + (size_t)b * NE;

    int ba = o0a, bb = o0b;
    int ra = chunk_load(csrb, ba, o1a, lane);
    int rb = chunk_load(csrb, bb, o1b, lane);

#define PROC(r_, m_, acc_) { \
    int mp = (m_) & ~3; \
    _Pragma("unroll 4") \
    for (int jj = 0; jj < mp; jj += 4) { \
        int row = __shfl((r_), jj + sub); \
        float4 v = *(const float4*)(yb + (size_t)row * NH + f4); \
        acc_.x += v.x; acc_.y += v.y; acc_.z += v.z; acc_.w += v.w; \
    } \
    if (mp < (m_)) { \
        int rem = (m_) - mp; \
        int row = __shfl((r_), mp + (sub < rem ? sub : 0)); \
        float4 v = *(const float4*)(yb + (size_t)row * NH + f4); \
        if (sub < rem) { acc_.x += v.x; acc_.y += v.y; acc_.z += v.z; acc_.w += v.w; } \
    } \
}

    while (ba < o1a || bb < o1b) {
        int ma = o1a - ba; ma = ma < 0 ? 0 : (ma > 64 ? 64 : ma);
        int mb = o1b - bb; mb = mb < 0 ? 0 : (mb > 64 ? 64 : mb);
        int ran = chunk_load(csrb, ba + 64, o1a, lane);   // prefetch next chunks
        int rbn = chunk_load(csrb, bb + 64, o1b, lane);
        PROC(ra, ma, acc0);
        PROC(rb, mb, acc1);
        ra = ran; rb = rbn; ba += 64; bb += 64;
    }
#undef PROC

    acc0.x += __shfl_xor(acc0.x, 16); acc0.y += __shfl_xor(acc0.y, 16);
    acc0.z += __shfl_xor(acc0.z, 16); acc0.w += __shfl_xor(acc0.w, 16);
    acc0.x += __shfl_xor(acc0.x, 32); acc0.y += __shfl_xor(acc0.y, 32);
    acc0.z += __shfl_xor(acc0.z, 32); acc0.w += __shfl_xor(acc0.w, 32);
    acc1.x += __shfl_xor(acc1.x, 16); acc1.y += __shfl_xor(acc1.y, 16);
    acc1.z += __shfl_xor(acc1.z, 16); acc1.w += __shfl_xor(acc1.w, 16);
    acc1.x += __shfl_xor(acc1.x, 32); acc1.y += __shfl_xor(acc1.y, 32);
    acc1.z += __shfl_xor(acc1.z, 32); acc1.w += __shfl_xor(acc1.w, 32);

    if (lane < 16) {
        float4 bi = *(const float4*)(bias + f4);
#pragma unroll
        for (int s2 = 0; s2 < 2; ++s2) {
            int n = s2 ? n1 : n0;
            float4 a = s2 ? acc1 : acc0;
            float d = dinv[b * NN + n];
            float4 o;
            o.x = fmaf(d, a.x, bi.x);
            o.y = fmaf(d, a.y, bi.y);
            o.z = fmaf(d, a.z, bi.z);
            o.w = fmaf(d, a.w, bi.w);
            if (LAYER == 1) {
                float4 m4 = *(const float4*)(mask + (size_t)n * NH + f4);
                o.x = fmaxf(o.x, 0.f) * m4.x;
                o.y = fmaxf(o.y, 0.f) * m4.y;
                o.z = fmaxf(o.z, 0.f) * m4.z;
                o.w = fmaxf(o.w, 0.f) * m4.w;
            }
            *(float4*)(out + ((size_t)b * NN + n) * NH + f4) = o;
        }
    }
}

extern "C" void kernel_launch(void* const* d_in, const int* in_sizes, int n_in,
                              void* d_out, int out_size, void* d_ws, size_t ws_size,
                              hipStream_t stream) {
    const float* xs = (const float*)d_in[0];
    const int*   ei = (const int*)d_in[1];
    const float* W1 = (const float*)d_in[2];
    const float* b1 = (const float*)d_in[3];
    const float* W2 = (const float*)d_in[4];
    const float* b2 = (const float*)d_in[5];
    float* out = (float*)d_out;

    float* ws   = (float*)d_ws;
    float* dinv = ws;
    int*   deg  = (int*)(ws + 80000);
    int*   flag = (int*)(ws + 160000);
    float* mask = ws + 160016;
    int*   offs = (int*)(ws + 1440016);
    int*   csr  = (int*)(ws + 1600024);
    float* y    = ws + 4160024;

    dim3 part_grid(NB * RNG);   // 256 workgroups, blockIdx&7 = graph (XCD-local)

    detect_kernel<<<1, 256, 0, stream>>>(ei, flag);
    mask_kernel<<<(NN * NH + 255) / 256, 256, 0, stream>>>(mask);
    hist_kernel<<<part_grid, 512, 0, stream>>>(ei, flag, deg);
    dinv_kernel<<<(NB * NN + 255) / 256, 256, 0, stream>>>(deg, dinv);
    scan_kernel<<<NB, 1024, 0, stream>>>(deg, offs);
    fill2_kernel<<<part_grid, 512, 0, stream>>>(ei, flag, offs, csr);

    dim3 gemm_grid(8 * ((NN + 63) / 64));   // blockIdx&7 = graph (XCD-local)
    dim3 agg_grid(NB * (5000 / 4));         // 10000 blocks, 4 waves x 2 nodes each

    // Layer 1: h -> d_out
    gemm_scale<<<gemm_grid, 256, 0, stream>>>(xs, W1, dinv, y);
    aggregate_half<1><<<agg_grid, 256, 0, stream>>>(y, offs, csr, dinv, b1, mask, out, 0);
    aggregate_half<1><<<agg_grid, 256, 0, stream>>>(y, offs, csr, dinv, b1, mask, out, 1);

    // Layer 2: reads h from d_out into y, then overwrites d_out
    gemm_scale<<<gemm_grid, 256, 0, stream>>>(out, W2, dinv, y);
    aggregate_half<2><<<agg_grid, 256, 0, stream>>>(y, offs, csr, dinv, b2, nullptr, out, 0);
    aggregate_half<2><<<agg_grid, 256, 0, stream>>>(y, offs, csr, dinv, b2, nullptr, out, 1);
}

// Round 10
// 459.119 us; speedup vs baseline: 1.5476x; 1.5476x over previous
//
#include <hip/hip_runtime.h>
#include <hip/hip_bf16.h>

#define NB 8
#define NN 10000
#define NE 320000
#define NF 128
#define NH 128

// ---------------- ws layout (float/int indices into ws) ----------------
// [0,        80000)    dinv    (NB*NN f32)
// [80000,   160000)    deg     (NB*NN i32)
// [160000,  160016)    flag    (i32 edge-dtype detect)
// [160016, 1440016)    mask    (NN*NH f32: 0.0 or 2.0)
// [1440016, 1520024)   offs    (NB*(NN+1) i32) CSR offsets per graph
// [1520024, 1600024)   cursor  (NB*NN i32)
// [1600024, 4160024)   csr     (NB*NE i32) source rows bucketed by dst
// [4160024, ...)       y = bf16[(X@W)*dinv[row]]  (NB*NN*NH bf16 = 20.5MB)

__device__ __forceinline__ int load_edge_nt(const int* ei, size_t idx, int is64) {
    if (is64) return (int)__builtin_nontemporal_load(((const long long*)ei) + idx);
    return __builtin_nontemporal_load(ei + idx);
}

__device__ __forceinline__ unsigned short f2bf(float x) {
    __hip_bfloat16 h = __float2bfloat16(x);   // RNE
    return *reinterpret_cast<unsigned short*>(&h);
}

// unpack uint = 2 bf16 (low ushort = even feat) and accumulate
__device__ __forceinline__ void bf2_add(float2& a, unsigned v) {
    union { unsigned u; float f; } lo, hi;
    lo.u = v << 16;
    hi.u = v & 0xffff0000u;
    a.x += lo.f;
    a.y += hi.f;
}

__global__ void detect_kernel(const int* __restrict__ ei, int* __restrict__ flag) {
    __shared__ int s;
    if (threadIdx.x == 0) s = 1;
    __syncthreads();
    int bad = 0;
    for (int q = threadIdx.x; q < 1024; q += 256)
        if (ei[2 * q + 1] != 0) bad = 1;
    if (bad) atomicAnd(&s, 0);
    __syncthreads();
    if (threadIdx.x == 0) *flag = s;   // 1 => int64 layout
}

// JAX threefry2x32, partitionable path: counter i -> (hi=0, lo=i), key (0,42),
// out = x0 ^ x1; keep <=> MSB==0; scale 2.0 (keep) else 0.0.
__global__ void mask_kernel(float* __restrict__ mask) {
    const unsigned TOT = NN * NH;
    unsigned i = blockIdx.x * 256 + threadIdx.x;
    if (i >= TOT) return;
    const unsigned ks0 = 0u, ks1 = 42u, ks2 = 0x1BD11BDAu ^ 0u ^ 42u;
    unsigned x0 = 0u + ks0;
    unsigned x1 = i + ks1;
#define TFR(r) { x0 += x1; x1 = (x1 << (r)) | (x1 >> (32 - (r))); x1 ^= x0; }
    TFR(13) TFR(15) TFR(26) TFR(6)
    x0 += ks1; x1 += ks2 + 1u;
    TFR(17) TFR(29) TFR(16) TFR(24)
    x0 += ks2; x1 += ks0 + 2u;
    TFR(13) TFR(15) TFR(26) TFR(6)
    x0 += ks0; x1 += ks1 + 3u;
    TFR(17) TFR(29) TFR(16) TFR(24)
    x0 += ks1; x1 += ks2 + 4u;
    TFR(13) TFR(15) TFR(26) TFR(6)
    x0 += ks2; x1 += ks0 + 5u;
#undef TFR
    unsigned bits = x0 ^ x1;
    mask[i] = (bits & 0x80000000u) ? 0.0f : 2.0f;
}

// XCD-local: blockIdx&7 = graph, so each graph's deg (40KB) stays in one L2.
__global__ __launch_bounds__(256) void deg_kernel(const int* __restrict__ ei,
                                                  const int* __restrict__ flag,
                                                  int* __restrict__ deg) {
    int b = blockIdx.x & 7;
    int e = (blockIdx.x >> 3) * 256 + threadIdx.x;
    if (e >= NE) return;
    int is64 = *flag;
    int col = load_edge_nt(ei, (size_t)b * 2 * NE + NE + e, is64);
    atomicAdd(&deg[b * NN + col], 1);
}

__global__ __launch_bounds__(256) void dinv_kernel(const int* __restrict__ deg,
                                                   float* __restrict__ dinv) {
    int i = blockIdx.x * 256 + threadIdx.x;
    if (i >= NB * NN) return;
    dinv[i] = 1.0f / sqrtf((float)(deg[i] + 1));  // +1 self-loop
}

// Exclusive prefix scan of deg per graph -> offs (and cursor copy). 1 block/graph.
__global__ __launch_bounds__(1024) void scan_kernel(const int* __restrict__ deg,
                                                    int* __restrict__ offs,
                                                    int* __restrict__ cursor) {
    int b = blockIdx.x;
    __shared__ int s[1024];
    int t = threadIdx.x;
    int carry = 0;
    for (int c0 = 0; c0 < NN; c0 += 1024) {
        int i = c0 + t;
        int v = (i < NN) ? deg[b * NN + i] : 0;
        s[t] = v;
        __syncthreads();
        int x = v;
        for (int off = 1; off < 1024; off <<= 1) {
            int add = (t >= off) ? s[t - off] : 0;
            __syncthreads();
            x += add;
            s[t] = x;
            __syncthreads();
        }
        int tot = s[1023];
        if (i < NN) {
            int e = carry + x - v;       // exclusive
            offs[b * (NN + 1) + i] = e;
            cursor[b * NN + i] = e;
        }
        carry += tot;
        __syncthreads();
    }
    if (t == 0) offs[b * (NN + 1) + NN] = carry;
}

// Bucket-fill CSR, XCD-local. HW model (r6/r7/r9 measured): scattered dword
// stores write through at partial-line granularity; atomics/warming don't fix
// it, and LDS-staged rescan (r9) trades it for worse latency starvation.
// ~100MB writes, ~110us — accepted cost.
__global__ __launch_bounds__(256) void fill_kernel(const int* __restrict__ ei,
                                                   const int* __restrict__ flag,
                                                   int* __restrict__ cursor,
                                                   int* __restrict__ csr) {
    int b = blockIdx.x & 7;
    int e = (blockIdx.x >> 3) * 256 + threadIdx.x;
    if (e >= NE) return;
    int is64 = *flag;
    size_t base = (size_t)b * 2 * NE;
    int row = load_edge_nt(ei, base + e, is64);
    int col = load_edge_nt(ei, base + NE + e, is64);
    int pos = atomicAdd(&cursor[b * NN + col], 1);
    csr[(size_t)b * NE + pos] = row;
}

// y = bf16[(X @ W) * dinv[row]].  blockIdx.x&7 = graph (XCD-local).
__global__ __launch_bounds__(256) void gemm_scale(const float* __restrict__ X,
                                                  const float* __restrict__ Wm,
                                                  const float* __restrict__ dinv,
                                                  unsigned short* __restrict__ y) {
    __shared__ float Xs[64][32];
    __shared__ float Ws[32][128];
    int b = blockIdx.x & 7;
    int row0 = (blockIdx.x >> 3) * 64;
    int t = threadIdx.x;
    int cg = t & 31;
    int rg = t >> 5;
    float acc[8][4] = {};
    const float* Xb = X + (size_t)b * NN * NF;

    for (int k0 = 0; k0 < NF; k0 += 32) {
        for (int q = t; q < 512; q += 256) {
            int r = q >> 3, c4 = q & 7;
            int gr = row0 + r;
            float4 v = make_float4(0.f, 0.f, 0.f, 0.f);
            if (gr < NN) v = *(const float4*)(Xb + (size_t)gr * NF + k0 + c4 * 4);
            *(float4*)&Xs[r][c4 * 4] = v;
        }
        for (int q = t; q < 1024; q += 256) {
            float4 v = *(const float4*)(Wm + k0 * NH + q * 4);
            *(float4*)(&Ws[0][0] + q * 4) = v;
        }
        __syncthreads();
#pragma unroll
        for (int kc = 0; kc < 32; kc += 4) {
            float4 xv[8];
#pragma unroll
            for (int i = 0; i < 8; ++i) xv[i] = *(const float4*)&Xs[rg * 8 + i][kc];
#pragma unroll
            for (int j = 0; j < 4; ++j) {
                float4 w = *(const float4*)&Ws[kc + j][cg * 4];
#pragma unroll
                for (int i = 0; i < 8; ++i) {
                    float xsv = (j == 0) ? xv[i].x : (j == 1) ? xv[i].y
                              : (j == 2) ? xv[i].z : xv[i].w;
                    acc[i][0] = fmaf(xsv, w.x, acc[i][0]);
                    acc[i][1] = fmaf(xsv, w.y, acc[i][1]);
                    acc[i][2] = fmaf(xsv, w.z, acc[i][2]);
                    acc[i][3] = fmaf(xsv, w.w, acc[i][3]);
                }
            }
        }
        __syncthreads();
    }
#pragma unroll
    for (int i = 0; i < 8; ++i) {
        int gr = row0 + rg * 8 + i;
        if (gr >= NN) continue;
        float d = dinv[b * NN + gr];
        ushort4 u;
        u.x = f2bf(acc[i][0] * d);
        u.y = f2bf(acc[i][1] * d);
        u.z = f2bf(acc[i][2] * d);
        u.w = f2bf(acc[i][3] * d);
        *(ushort4*)(y + ((size_t)b * NN + gr) * NH + cg * 4) = u;
    }
}

// Gather-reduce, full 128-feat row per edge: 64 lanes x uint (2 bf16) = 256B
// = 2 cache lines per edge (fp32 was 4) — halves L2 line traffic, load-instr
// count, and dispatch count. One wave per TWO nodes (idx, idx+5000) for ILP.
// blockIdx&7 = graph -> per-graph y (2.56MB bf16) resident in XCD L2.
template<int LAYER>
__global__ __launch_bounds__(256) void aggregate_full(const unsigned short* __restrict__ y,
                                                      const int* __restrict__ offs,
                                                      const int* __restrict__ csr,
                                                      const float* __restrict__ dinv,
                                                      const float* __restrict__ bias,
                                                      const float* __restrict__ mask,
                                                      float* __restrict__ out) {
    int b = blockIdx.x & 7;
    int w = threadIdx.x >> 6;
    int idx = (blockIdx.x >> 3) * 4 + w;     // [0, 5000)
    int n0 = idx, n1 = idx + 5000;
    int lane = threadIdx.x & 63;
    const unsigned* yb = (const unsigned*)(y + (size_t)b * NN * NH);  // 64 uints/row

    // self-loop init
    float2 acc0 = make_float2(0.f, 0.f);
    float2 acc1 = make_float2(0.f, 0.f);
    bf2_add(acc0, yb[(size_t)n0 * 64 + lane]);
    bf2_add(acc1, yb[(size_t)n1 * 64 + lane]);

    const int* ob = offs + b * (NN + 1);
    int ba = ob[n0], o1a = ob[n0 + 1];
    int bb = ob[n1], o1b = ob[n1 + 1];
    const int* csrb = csr + (size_t)b * NE;

    while (ba < o1a || bb < o1b) {
        int ma = o1a - ba; ma = ma < 0 ? 0 : (ma > 64 ? 64 : ma);
        int mb = o1b - bb; mb = mb < 0 ? 0 : (mb > 64 ? 64 : mb);
        int ra = (lane < ma) ? csrb[ba + lane] : 0;
        int rb = (lane < mb) ? csrb[bb + lane] : 0;
        int mmin = ma < mb ? ma : mb;
        int jj = 0;
#pragma unroll 4
        for (; jj < mmin; ++jj) {            // two independent gather streams
            int r0 = __shfl(ra, jj);
            int r1 = __shfl(rb, jj);
            unsigned u0 = yb[(size_t)r0 * 64 + lane];
            unsigned u1 = yb[(size_t)r1 * 64 + lane];
            bf2_add(acc0, u0);
            bf2_add(acc1, u1);
        }
#pragma unroll 4
        for (; jj < ma; ++jj) {
            int r0 = __shfl(ra, jj);
            bf2_add(acc0, yb[(size_t)r0 * 64 + lane]);
        }
#pragma unroll 4
        for (; jj < mb; ++jj) {
            int r1 = __shfl(rb, jj);
            bf2_add(acc1, yb[(size_t)r1 * 64 + lane]);
        }
        ba += 64; bb += 64;
    }

    float2 bi = *(const float2*)(bias + lane * 2);
#pragma unroll
    for (int s2 = 0; s2 < 2; ++s2) {
        int n = s2 ? n1 : n0;
        float2 a = s2 ? acc1 : acc0;
        float d = dinv[b * NN + n];
        float2 o;
        o.x = fmaf(d, a.x, bi.x);
        o.y = fmaf(d, a.y, bi.y);
        if (LAYER == 1) {
            float2 m2 = *(const float2*)(mask + (size_t)n * NH + lane * 2);
            o.x = fmaxf(o.x, 0.f) * m2.x;
            o.y = fmaxf(o.y, 0.f) * m2.y;
        }
        *(float2*)(out + ((size_t)b * NN + n) * NH + lane * 2) = o;
    }
}

extern "C" void kernel_launch(void* const* d_in, const int* in_sizes, int n_in,
                              void* d_out, int out_size, void* d_ws, size_t ws_size,
                              hipStream_t stream) {
    const float* xs = (const float*)d_in[0];
    const int*   ei = (const int*)d_in[1];
    const float* W1 = (const float*)d_in[2];
    const float* b1 = (const float*)d_in[3];
    const float* W2 = (const float*)d_in[4];
    const float* b2 = (const float*)d_in[5];
    float* out = (float*)d_out;

    float* ws     = (float*)d_ws;
    float* dinv   = ws;
    int*   deg    = (int*)(ws + 80000);
    int*   flag   = (int*)(ws + 160000);
    float* mask   = ws + 160016;
    int*   offs   = (int*)(ws + 1440016);
    int*   cursor = (int*)(ws + 1520024);
    int*   csr    = (int*)(ws + 1600024);
    unsigned short* y = (unsigned short*)(ws + 4160024);

    dim3 edge_grid(8 * ((NE + 255) / 256));       // blockIdx&7 = graph (XCD-local)

    hipMemsetAsync(deg, 0, (size_t)NB * NN * sizeof(int), stream);
    detect_kernel<<<1, 256, 0, stream>>>(ei, flag);
    mask_kernel<<<(NN * NH + 255) / 256, 256, 0, stream>>>(mask);
    deg_kernel<<<edge_grid, 256, 0, stream>>>(ei, flag, deg);
    dinv_kernel<<<(NB * NN + 255) / 256, 256, 0, stream>>>(deg, dinv);
    scan_kernel<<<NB, 1024, 0, stream>>>(deg, offs, cursor);
    fill_kernel<<<edge_grid, 256, 0, stream>>>(ei, flag, cursor, csr);

    dim3 gemm_grid(8 * ((NN + 63) / 64));   // blockIdx&7 = graph (XCD-local)
    dim3 agg_grid(NB * (5000 / 4));         // 10000 blocks, 4 waves x 2 nodes each

    // Layer 1: h -> d_out
    gemm_scale<<<gemm_grid, 256, 0, stream>>>(xs, W1, dinv, y);
    aggregate_full<1><<<agg_grid, 256, 0, stream>>>(y, offs, csr, dinv, b1, mask, out);

    // Layer 2: reads h from d_out into y, then overwrites d_out
    gemm_scale<<<gemm_grid, 256, 0, stream>>>(out, W2, dinv, y);
    aggregate_full<2><<<agg_grid, 256, 0, stream>>>(y, offs, csr, dinv, b2, nullptr, out);
}

// Round 11
// 285.617 us; speedup vs baseline: 2.4878x; 1.6075x over previous
//
#include <hip/hip_runtime.h>
#include <hip/hip_bf16.h>

#define NB 8
#define NN 10000
#define NE 320000
#define NF 128
#define NH 128
#define RNG 32            // node ranges (buckets) per graph
#define RS 313            // ceil(NN/RNG)
#define BCAP 12288        // per-bucket capacity; mean 10000, sigma ~98 -> +23 sigma
#define P1E 8000          // edges per pass-1 block
#define P1CAP 512         // pass-1 LDS slots per bucket; mean 250, sigma ~16

// ---------------- ws layout (float indices into ws) ----------------
// [0,        80000)     dinv    (NB*NN f32)
// [80000,   160000)     deg     (NB*NN i32)
// [160000,  160016)     flag    (i32 edge-dtype detect)
// [160016,  1440016)    mask    (NN*NH f32: 0.0 or 2.0)
// [1440016, 1520016)    offs    (NB*NN i32, ABSOLUTE index into csr)
// [1520016, 1520272)    gcur    (NB*RNG i32 bucket cursors)
// [1520272, 4666000)    gbucket (NB*RNG*BCAP u32 packed col<<14|row)
// [4666000, 7811728)    csr     (NB*RNG*BCAP i32 rows, BCAP-strided regions)
// [7811728, 10371728)   y       (NB*NN*NH bf16 = 20.5MB)

__device__ __forceinline__ int load_edge_nt(const int* ei, size_t idx, int is64) {
    if (is64) return (int)__builtin_nontemporal_load(((const long long*)ei) + idx);
    return __builtin_nontemporal_load(ei + idx);
}

__device__ __forceinline__ unsigned short f2bf(float x) {
    __hip_bfloat16 h = __float2bfloat16(x);   // RNE
    return *reinterpret_cast<unsigned short*>(&h);
}

__device__ __forceinline__ void bf2_add(float2& a, unsigned v) {
    union { unsigned u; float f; } lo, hi;
    lo.u = v << 16;
    hi.u = v & 0xffff0000u;
    a.x += lo.f;
    a.y += hi.f;
}

__global__ void detect_kernel(const int* __restrict__ ei, int* __restrict__ flag) {
    __shared__ int s;
    if (threadIdx.x == 0) s = 1;
    __syncthreads();
    int bad = 0;
    for (int q = threadIdx.x; q < 1024; q += 256)
        if (ei[2 * q + 1] != 0) bad = 1;
    if (bad) atomicAnd(&s, 0);
    __syncthreads();
    if (threadIdx.x == 0) *flag = s;   // 1 => int64 layout
}

// JAX threefry2x32, partitionable path: counter i -> (hi=0, lo=i), key (0,42),
// out = x0 ^ x1; keep <=> MSB==0; scale 2.0 (keep) else 0.0.
__global__ void mask_kernel(float* __restrict__ mask) {
    const unsigned TOT = NN * NH;
    unsigned i = blockIdx.x * 256 + threadIdx.x;
    if (i >= TOT) return;
    const unsigned ks0 = 0u, ks1 = 42u, ks2 = 0x1BD11BDAu ^ 0u ^ 42u;
    unsigned x0 = 0u + ks0;
    unsigned x1 = i + ks1;
#define TFR(r) { x0 += x1; x1 = (x1 << (r)) | (x1 >> (32 - (r))); x1 ^= x0; }
    TFR(13) TFR(15) TFR(26) TFR(6)
    x0 += ks1; x1 += ks2 + 1u;
    TFR(17) TFR(29) TFR(16) TFR(24)
    x0 += ks2; x1 += ks0 + 2u;
    TFR(13) TFR(15) TFR(26) TFR(6)
    x0 += ks0; x1 += ks1 + 3u;
    TFR(17) TFR(29) TFR(16) TFR(24)
    x0 += ks1; x1 += ks2 + 4u;
    TFR(13) TFR(15) TFR(26) TFR(6)
    x0 += ks2; x1 += ks0 + 5u;
#undef TFR
    unsigned bits = x0 ^ x1;
    mask[i] = (bits & 0x80000000u) ? 0.0f : 2.0f;
}

// Pass 1: read edges ONCE, bin into 32 node-range buckets in LDS, append each
// segment to the graph's global bucket region with coalesced ~1KB runs.
// Fixes r4-r7 fill (scattered dword write-through) without r9's 32x rescan.
__global__ __launch_bounds__(256) void part_kernel(const int* __restrict__ ei,
                                                   const int* __restrict__ flag,
                                                   int* __restrict__ gcur,
                                                   unsigned* __restrict__ gbucket) {
    int b = blockIdx.x & 7;                       // graph (XCD-local)
    int chunk = blockIdx.x >> 3;                  // 0..39
    int e0 = chunk * P1E, e1 = e0 + P1E;
    __shared__ int bcnt[RNG];
    __shared__ unsigned bbuf[RNG][P1CAP];
    for (int i = threadIdx.x; i < RNG; i += 256) bcnt[i] = 0;
    __syncthreads();
    int is64 = *flag;
    size_t base = (size_t)b * 2 * NE;
    for (int e = e0 + threadIdx.x; e < e1; e += 256) {
        int row = load_edge_nt(ei, base + e, is64);
        int col = load_edge_nt(ei, base + NE + e, is64);
        int bk = col / RS;                        // magic-mul division
        unsigned pk = ((unsigned)col << 14) | (unsigned)row;
        int p = atomicAdd(&bcnt[bk], 1);
        if (p < P1CAP) bbuf[bk][p] = pk;
        else {                                    // statistically never
            int gp = atomicAdd(&gcur[b * RNG + bk], 1);
            if (gp < BCAP) gbucket[(size_t)(b * RNG + bk) * BCAP + gp] = pk;
        }
    }
    __syncthreads();
    int wave = threadIdx.x >> 6, lane = threadIdx.x & 63;
    for (int bk = wave; bk < RNG; bk += 4) {
        int len = bcnt[bk]; if (len > P1CAP) len = P1CAP;
        int gb = 0;
        if (lane == 0) gb = atomicAdd(&gcur[b * RNG + bk], len);
        gb = __shfl(gb, 0);
        unsigned* dst = gbucket + (size_t)(b * RNG + bk) * BCAP;
        for (int i = lane; i < len; i += 64)
            if (gb + i < BCAP) dst[gb + i] = bbuf[bk][i];
    }
}

// Pass 2: one block per (graph,range). Read bucket (~10K edges, L2-hot),
// LDS hist -> block scan -> LDS scatter -> coalesced csr copy-out.
// Emits deg and ABSOLUTE offs as byproducts (deg/scan/fill kernels deleted).
__global__ __launch_bounds__(512) void build_kernel(const unsigned* __restrict__ gbucket,
                                                    const int* __restrict__ gcur,
                                                    int* __restrict__ csr,
                                                    int* __restrict__ deg,
                                                    int* __restrict__ offs) {
    int b = blockIdx.x & 7;
    int r = blockIdx.x >> 3;                      // 0..31
    int n0 = r * RS;
    int nloc = (NN - n0 < RS) ? (NN - n0) : RS;
    __shared__ int cnt[512];
    __shared__ int cur[RS];
    __shared__ int buf[BCAP];
    int gidx = b * RNG + r;
    int K = gcur[gidx]; if (K > BCAP) K = BCAP;
    const unsigned* src = gbucket + (size_t)gidx * BCAP;
    int t = threadIdx.x;
    cnt[t] = 0;
    __syncthreads();
    for (int i = t; i < K; i += 512)
        atomicAdd(&cnt[(src[i] >> 14) - n0], 1);
    __syncthreads();
    int v = cnt[t];
    __syncthreads();
    // Hillis-Steele inclusive scan over 512
    int x = v;
    cnt[t] = x;
    __syncthreads();
    for (int off = 1; off < 512; off <<= 1) {
        int add = (t >= off) ? cnt[t - off] : 0;
        __syncthreads();
        x += add;
        cnt[t] = x;
        __syncthreads();
    }
    int excl = x - v;
    if (t < nloc) {
        deg[b * NN + n0 + t] = v;
        offs[b * NN + n0 + t] = gidx * BCAP + excl;   // absolute into csr
        cur[t] = excl;
    }
    __syncthreads();
    for (int i = t; i < K; i += 512) {
        unsigned pk = src[i];
        int p = atomicAdd(&cur[(pk >> 14) - n0], 1);
        buf[p] = (int)(pk & 16383u);
    }
    __syncthreads();
    int* dstc = csr + (size_t)gidx * BCAP;
    for (int i = t; i < K; i += 512) dstc[i] = buf[i];   // coalesced
}

__global__ __launch_bounds__(256) void dinv_kernel(const int* __restrict__ deg,
                                                   float* __restrict__ dinv) {
    int i = blockIdx.x * 256 + threadIdx.x;
    if (i >= NB * NN) return;
    dinv[i] = 1.0f / sqrtf((float)(deg[i] + 1));  // +1 self-loop
}

// y = bf16[(X @ W) * dinv[row]].  blockIdx.x&7 = graph (XCD-local).
__global__ __launch_bounds__(256) void gemm_scale(const float* __restrict__ X,
                                                  const float* __restrict__ Wm,
                                                  const float* __restrict__ dinv,
                                                  unsigned short* __restrict__ y) {
    __shared__ float Xs[64][32];
    __shared__ float Ws[32][128];
    int b = blockIdx.x & 7;
    int row0 = (blockIdx.x >> 3) * 64;
    int t = threadIdx.x;
    int cg = t & 31;
    int rg = t >> 5;
    float acc[8][4] = {};
    const float* Xb = X + (size_t)b * NN * NF;

    for (int k0 = 0; k0 < NF; k0 += 32) {
        for (int q = t; q < 512; q += 256) {
            int r = q >> 3, c4 = q & 7;
            int gr = row0 + r;
            float4 v = make_float4(0.f, 0.f, 0.f, 0.f);
            if (gr < NN) v = *(const float4*)(Xb + (size_t)gr * NF + k0 + c4 * 4);
            *(float4*)&Xs[r][c4 * 4] = v;
        }
        for (int q = t; q < 1024; q += 256) {
            float4 v = *(const float4*)(Wm + k0 * NH + q * 4);
            *(float4*)(&Ws[0][0] + q * 4) = v;
        }
        __syncthreads();
#pragma unroll
        for (int kc = 0; kc < 32; kc += 4) {
            float4 xv[8];
#pragma unroll
            for (int i = 0; i < 8; ++i) xv[i] = *(const float4*)&Xs[rg * 8 + i][kc];
#pragma unroll
            for (int j = 0; j < 4; ++j) {
                float4 w = *(const float4*)&Ws[kc + j][cg * 4];
#pragma unroll
                for (int i = 0; i < 8; ++i) {
                    float xsv = (j == 0) ? xv[i].x : (j == 1) ? xv[i].y
                              : (j == 2) ? xv[i].z : xv[i].w;
                    acc[i][0] = fmaf(xsv, w.x, acc[i][0]);
                    acc[i][1] = fmaf(xsv, w.y, acc[i][1]);
                    acc[i][2] = fmaf(xsv, w.z, acc[i][2]);
                    acc[i][3] = fmaf(xsv, w.w, acc[i][3]);
                }
            }
        }
        __syncthreads();
    }
#pragma unroll
    for (int i = 0; i < 8; ++i) {
        int gr = row0 + rg * 8 + i;
        if (gr >= NN) continue;
        float d = dinv[b * NN + gr];
        ushort4 u;
        u.x = f2bf(acc[i][0] * d);
        u.y = f2bf(acc[i][1] * d);
        u.z = f2bf(acc[i][2] * d);
        u.w = f2bf(acc[i][3] * d);
        *(ushort4*)(y + ((size_t)b * NN + gr) * NH + cg * 4) = u;
    }
}

// Gather-reduce, full 128-feat row per edge (64 lanes x 2 bf16 = 256B).
// offs is ABSOLUTE into csr; range length from deg. Two nodes per wave (ILP).
template<int LAYER>
__global__ __launch_bounds__(256) void aggregate_full(const unsigned short* __restrict__ y,
                                                      const int* __restrict__ offs,
                                                      const int* __restrict__ deg,
                                                      const int* __restrict__ csr,
                                                      const float* __restrict__ dinv,
                                                      const float* __restrict__ bias,
                                                      const float* __restrict__ mask,
                                                      float* __restrict__ out) {
    int b = blockIdx.x & 7;
    int w = threadIdx.x >> 6;
    int idx = (blockIdx.x >> 3) * 4 + w;     // [0, 5000)
    int n0 = idx, n1 = idx + 5000;
    int lane = threadIdx.x & 63;
    const unsigned* yb = (const unsigned*)(y + (size_t)b * NN * NH);  // 64 uints/row

    float2 acc0 = make_float2(0.f, 0.f);
    float2 acc1 = make_float2(0.f, 0.f);
    bf2_add(acc0, yb[(size_t)n0 * 64 + lane]);   // self-loop
    bf2_add(acc1, yb[(size_t)n1 * 64 + lane]);

    const int* ob = offs + b * NN;
    const int* db = deg + b * NN;
    int ba = ob[n0], o1a = ba + db[n0];
    int bb = ob[n1], o1b = bb + db[n1];

    while (ba < o1a || bb < o1b) {
        int ma = o1a - ba; ma = ma < 0 ? 0 : (ma > 64 ? 64 : ma);
        int mb = o1b - bb; mb = mb < 0 ? 0 : (mb > 64 ? 64 : mb);
        int ra = (lane < ma) ? csr[ba + lane] : 0;
        int rb = (lane < mb) ? csr[bb + lane] : 0;
        int mmin = ma < mb ? ma : mb;
        int jj = 0;
#pragma unroll 4
        for (; jj < mmin; ++jj) {                // two independent gather streams
            int r0 = __shfl(ra, jj);
            int r1 = __shfl(rb, jj);
            unsigned u0 = yb[(size_t)r0 * 64 + lane];
            unsigned u1 = yb[(size_t)r1 * 64 + lane];
            bf2_add(acc0, u0);
            bf2_add(acc1, u1);
        }
#pragma unroll 4
        for (; jj < ma; ++jj) {
            int r0 = __shfl(ra, jj);
            bf2_add(acc0, yb[(size_t)r0 * 64 + lane]);
        }
#pragma unroll 4
        for (; jj < mb; ++jj) {
            int r1 = __shfl(rb, jj);
            bf2_add(acc1, yb[(size_t)r1 * 64 + lane]);
        }
        ba += 64; bb += 64;
    }

    float2 bi = *(const float2*)(bias + lane * 2);
#pragma unroll
    for (int s2 = 0; s2 < 2; ++s2) {
        int n = s2 ? n1 : n0;
        float2 a = s2 ? acc1 : acc0;
        float d = dinv[b * NN + n];
        float2 o;
        o.x = fmaf(d, a.x, bi.x);
        o.y = fmaf(d, a.y, bi.y);
        if (LAYER == 1) {
            float2 m2 = *(const float2*)(mask + (size_t)n * NH + lane * 2);
            o.x = fmaxf(o.x, 0.f) * m2.x;
            o.y = fmaxf(o.y, 0.f) * m2.y;
        }
        *(float2*)(out + ((size_t)b * NN + n) * NH + lane * 2) = o;
    }
}

extern "C" void kernel_launch(void* const* d_in, const int* in_sizes, int n_in,
                              void* d_out, int out_size, void* d_ws, size_t ws_size,
                              hipStream_t stream) {
    const float* xs = (const float*)d_in[0];
    const int*   ei = (const int*)d_in[1];
    const float* W1 = (const float*)d_in[2];
    const float* b1 = (const float*)d_in[3];
    const float* W2 = (const float*)d_in[4];
    const float* b2 = (const float*)d_in[5];
    float* out = (float*)d_out;

    float* ws        = (float*)d_ws;
    float* dinv      = ws;
    int*   deg       = (int*)(ws + 80000);
    int*   flag      = (int*)(ws + 160000);
    float* mask      = ws + 160016;
    int*   offs      = (int*)(ws + 1440016);
    int*   gcur      = (int*)(ws + 1520016);
    unsigned* gbucket= (unsigned*)(ws + 1520272);
    int*   csr       = (int*)(ws + 4666000);
    unsigned short* y= (unsigned short*)(ws + 7811728);

    hipMemsetAsync(gcur, 0, NB * RNG * sizeof(int), stream);
    detect_kernel<<<1, 256, 0, stream>>>(ei, flag);
    mask_kernel<<<(NN * NH + 255) / 256, 256, 0, stream>>>(mask);
    part_kernel<<<8 * (NE / P1E), 256, 0, stream>>>(ei, flag, gcur, gbucket);
    build_kernel<<<NB * RNG, 512, 0, stream>>>(gbucket, gcur, csr, deg, offs);
    dinv_kernel<<<(NB * NN + 255) / 256, 256, 0, stream>>>(deg, dinv);

    dim3 gemm_grid(8 * ((NN + 63) / 64));   // blockIdx&7 = graph (XCD-local)
    dim3 agg_grid(NB * (5000 / 4));         // 10000 blocks, 4 waves x 2 nodes each

    // Layer 1: h -> d_out
    gemm_scale<<<gemm_grid, 256, 0, stream>>>(xs, W1, dinv, y);
    aggregate_full<1><<<agg_grid, 256, 0, stream>>>(y, offs, deg, csr, dinv, b1, mask, out);

    // Layer 2: reads h from d_out into y, then overwrites d_out
    gemm_scale<<<gemm_grid, 256, 0, stream>>>(out, W2, dinv, y);
    aggregate_full<2><<<agg_grid, 256, 0, stream>>>(y, offs, deg, csr, dinv, b2, nullptr, out);
}

// Round 12
// 281.145 us; speedup vs baseline: 2.5273x; 1.0159x over previous
//
#include <hip/hip_runtime.h>
#include <hip/hip_bf16.h>

#define NB 8
#define NN 10000
#define NE 320000
#define NF 128
#define NH 128
#define RNG 32            // node ranges (buckets) per graph
#define RS 313            // ceil(NN/RNG)
#define BCAP 12288        // per-bucket capacity; mean 10000, sigma ~98 -> +23 sigma
#define P1E 8000          // edges per pass-1 block
#define P1CAP 512         // pass-1 LDS slots per bucket; mean 250, sigma ~16

// ---------------- ws layout (float indices into ws) ----------------
// [0,        80000)     dinv    (NB*NN f32)
// [80000,   160000)     deg     (NB*NN i32)
// [160000,  160016)     flag    (i32 edge-dtype detect)
// [160016,  1440016)    mask    (NN*NH f32: 0.0 or 2.0)
// [1440016, 1520016)    offs    (NB*NN i32, ABSOLUTE index into csr)
// [1520016, 1520272)    gcur    (NB*RNG i32 bucket cursors)
// [1520272, 4666000)    gbucket (NB*RNG*BCAP u32 packed col<<14|row)
// [4666000, 7811728)    csr     (NB*RNG*BCAP i32 BYTE offsets row*256)
// [7811728, 10371728)   y       (NB*NN*NH bf16 = 20.5MB)

__device__ __forceinline__ int load_edge_nt(const int* ei, size_t idx, int is64) {
    if (is64) return (int)__builtin_nontemporal_load(((const long long*)ei) + idx);
    return __builtin_nontemporal_load(ei + idx);
}

__device__ __forceinline__ unsigned short f2bf(float x) {
    __hip_bfloat16 h = __float2bfloat16(x);   // RNE
    return *reinterpret_cast<unsigned short*>(&h);
}

__device__ __forceinline__ void bf2_add(float2& a, unsigned v) {
    union { unsigned u; float f; } lo, hi;
    lo.u = v << 16;
    hi.u = v & 0xffff0000u;
    a.x += lo.f;
    a.y += hi.f;
}

__global__ void detect_kernel(const int* __restrict__ ei, int* __restrict__ flag) {
    __shared__ int s;
    if (threadIdx.x == 0) s = 1;
    __syncthreads();
    int bad = 0;
    for (int q = threadIdx.x; q < 1024; q += 256)
        if (ei[2 * q + 1] != 0) bad = 1;
    if (bad) atomicAnd(&s, 0);
    __syncthreads();
    if (threadIdx.x == 0) *flag = s;   // 1 => int64 layout
}

// JAX threefry2x32, partitionable path: counter i -> (hi=0, lo=i), key (0,42),
// out = x0 ^ x1; keep <=> MSB==0; scale 2.0 (keep) else 0.0.
__global__ void mask_kernel(float* __restrict__ mask) {
    const unsigned TOT = NN * NH;
    unsigned i = blockIdx.x * 256 + threadIdx.x;
    if (i >= TOT) return;
    const unsigned ks0 = 0u, ks1 = 42u, ks2 = 0x1BD11BDAu ^ 0u ^ 42u;
    unsigned x0 = 0u + ks0;
    unsigned x1 = i + ks1;
#define TFR(r) { x0 += x1; x1 = (x1 << (r)) | (x1 >> (32 - (r))); x1 ^= x0; }
    TFR(13) TFR(15) TFR(26) TFR(6)
    x0 += ks1; x1 += ks2 + 1u;
    TFR(17) TFR(29) TFR(16) TFR(24)
    x0 += ks2; x1 += ks0 + 2u;
    TFR(13) TFR(15) TFR(26) TFR(6)
    x0 += ks0; x1 += ks1 + 3u;
    TFR(17) TFR(29) TFR(16) TFR(24)
    x0 += ks1; x1 += ks2 + 4u;
    TFR(13) TFR(15) TFR(26) TFR(6)
    x0 += ks2; x1 += ks0 + 5u;
#undef TFR
    unsigned bits = x0 ^ x1;
    mask[i] = (bits & 0x80000000u) ? 0.0f : 2.0f;
}

// Pass 1: read edges ONCE, bin into 32 node-range buckets in LDS, append each
// segment to the graph's global bucket region with coalesced ~1KB runs.
__global__ __launch_bounds__(256) void part_kernel(const int* __restrict__ ei,
                                                   const int* __restrict__ flag,
                                                   int* __restrict__ gcur,
                                                   unsigned* __restrict__ gbucket) {
    int b = blockIdx.x & 7;                       // graph (XCD-local)
    int chunk = blockIdx.x >> 3;                  // 0..39
    int e0 = chunk * P1E, e1 = e0 + P1E;
    __shared__ int bcnt[RNG];
    __shared__ unsigned bbuf[RNG][P1CAP];
    for (int i = threadIdx.x; i < RNG; i += 256) bcnt[i] = 0;
    __syncthreads();
    int is64 = *flag;
    size_t base = (size_t)b * 2 * NE;
    for (int e = e0 + threadIdx.x; e < e1; e += 256) {
        int row = load_edge_nt(ei, base + e, is64);
        int col = load_edge_nt(ei, base + NE + e, is64);
        int bk = col / RS;                        // magic-mul division
        unsigned pk = ((unsigned)col << 14) | (unsigned)row;
        int p = atomicAdd(&bcnt[bk], 1);
        if (p < P1CAP) bbuf[bk][p] = pk;
        else {                                    // statistically never
            int gp = atomicAdd(&gcur[b * RNG + bk], 1);
            if (gp < BCAP) gbucket[(size_t)(b * RNG + bk) * BCAP + gp] = pk;
        }
    }
    __syncthreads();
    int wave = threadIdx.x >> 6, lane = threadIdx.x & 63;
    for (int bk = wave; bk < RNG; bk += 4) {
        int len = bcnt[bk]; if (len > P1CAP) len = P1CAP;
        int gb = 0;
        if (lane == 0) gb = atomicAdd(&gcur[b * RNG + bk], len);
        gb = __shfl(gb, 0);
        unsigned* dst = gbucket + (size_t)(b * RNG + bk) * BCAP;
        for (int i = lane; i < len; i += 64)
            if (gb + i < BCAP) dst[gb + i] = bbuf[bk][i];
    }
}

// Pass 2: one block per (graph,range). Read bucket (~10K edges, L2-hot),
// LDS hist -> block scan -> LDS scatter -> coalesced csr copy-out.
// csr entries are PRE-SCALED BYTE OFFSETS (row*256) so the aggregate's
// per-edge address math is a single v_add_u32 (r11: addr chain was ~5/13
// VALU instrs per edge).
__global__ __launch_bounds__(512) void build_kernel(const unsigned* __restrict__ gbucket,
                                                    const int* __restrict__ gcur,
                                                    int* __restrict__ csr,
                                                    int* __restrict__ deg,
                                                    int* __restrict__ offs) {
    int b = blockIdx.x & 7;
    int r = blockIdx.x >> 3;                      // 0..31
    int n0 = r * RS;
    int nloc = (NN - n0 < RS) ? (NN - n0) : RS;
    __shared__ int cnt[512];
    __shared__ int cur[RS];
    __shared__ int buf[BCAP];
    int gidx = b * RNG + r;
    int K = gcur[gidx]; if (K > BCAP) K = BCAP;
    const unsigned* src = gbucket + (size_t)gidx * BCAP;
    int t = threadIdx.x;
    cnt[t] = 0;
    __syncthreads();
    for (int i = t; i < K; i += 512)
        atomicAdd(&cnt[(src[i] >> 14) - n0], 1);
    __syncthreads();
    int v = cnt[t];
    __syncthreads();
    // Hillis-Steele inclusive scan over 512
    int x = v;
    cnt[t] = x;
    __syncthreads();
    for (int off = 1; off < 512; off <<= 1) {
        int add = (t >= off) ? cnt[t - off] : 0;
        __syncthreads();
        x += add;
        cnt[t] = x;
        __syncthreads();
    }
    int excl = x - v;
    if (t < nloc) {
        deg[b * NN + n0 + t] = v;
        offs[b * NN + n0 + t] = gidx * BCAP + excl;   // absolute into csr
        cur[t] = excl;
    }
    __syncthreads();
    for (int i = t; i < K; i += 512) {
        unsigned pk = src[i];
        int p = atomicAdd(&cur[(pk >> 14) - n0], 1);
        buf[p] = (int)((pk & 16383u) << 8);           // row*256 byte offset
    }
    __syncthreads();
    int* dstc = csr + (size_t)gidx * BCAP;
    for (int i = t; i < K; i += 512) dstc[i] = buf[i];   // coalesced
}

__global__ __launch_bounds__(256) void dinv_kernel(const int* __restrict__ deg,
                                                   float* __restrict__ dinv) {
    int i = blockIdx.x * 256 + threadIdx.x;
    if (i >= NB * NN) return;
    dinv[i] = 1.0f / sqrtf((float)(deg[i] + 1));  // +1 self-loop
}

// y = bf16[(X @ W) * dinv[row]].  blockIdx.x&7 = graph (XCD-local).
__global__ __launch_bounds__(256) void gemm_scale(const float* __restrict__ X,
                                                  const float* __restrict__ Wm,
                                                  const float* __restrict__ dinv,
                                                  unsigned short* __restrict__ y) {
    __shared__ float Xs[64][32];
    __shared__ float Ws[32][128];
    int b = blockIdx.x & 7;
    int row0 = (blockIdx.x >> 3) * 64;
    int t = threadIdx.x;
    int cg = t & 31;
    int rg = t >> 5;
    float acc[8][4] = {};
    const float* Xb = X + (size_t)b * NN * NF;

    for (int k0 = 0; k0 < NF; k0 += 32) {
        for (int q = t; q < 512; q += 256) {
            int r = q >> 3, c4 = q & 7;
            int gr = row0 + r;
            float4 v = make_float4(0.f, 0.f, 0.f, 0.f);
            if (gr < NN) v = *(const float4*)(Xb + (size_t)gr * NF + k0 + c4 * 4);
            *(float4*)&Xs[r][c4 * 4] = v;
        }
        for (int q = t; q < 1024; q += 256) {
            float4 v = *(const float4*)(Wm + k0 * NH + q * 4);
            *(float4*)(&Ws[0][0] + q * 4) = v;
        }
        __syncthreads();
#pragma unroll
        for (int kc = 0; kc < 32; kc += 4) {
            float4 xv[8];
#pragma unroll
            for (int i = 0; i < 8; ++i) xv[i] = *(const float4*)&Xs[rg * 8 + i][kc];
#pragma unroll
            for (int j = 0; j < 4; ++j) {
                float4 w = *(const float4*)&Ws[kc + j][cg * 4];
#pragma unroll
                for (int i = 0; i < 8; ++i) {
                    float xsv = (j == 0) ? xv[i].x : (j == 1) ? xv[i].y
                              : (j == 2) ? xv[i].z : xv[i].w;
                    acc[i][0] = fmaf(xsv, w.x, acc[i][0]);
                    acc[i][1] = fmaf(xsv, w.y, acc[i][1]);
                    acc[i][2] = fmaf(xsv, w.z, acc[i][2]);
                    acc[i][3] = fmaf(xsv, w.w, acc[i][3]);
                }
            }
        }
        __syncthreads();
    }
#pragma unroll
    for (int i = 0; i < 8; ++i) {
        int gr = row0 + rg * 8 + i;
        if (gr >= NN) continue;
        float d = dinv[b * NN + gr];
        ushort4 u;
        u.x = f2bf(acc[i][0] * d);
        u.y = f2bf(acc[i][1] * d);
        u.z = f2bf(acc[i][2] * d);
        u.w = f2bf(acc[i][3] * d);
        *(ushort4*)(y + ((size_t)b * NN + gr) * NH + cg * 4) = u;
    }
}

// Gather-reduce, full 128-feat row per edge (64 lanes x 2 bf16 = 256B).
// csr holds BYTE offsets (row*256): per-edge address = one v_add_u32 against
// loop-invariant lane4, SGPR-base global load. Two nodes per wave (ILP).
template<int LAYER>
__global__ __launch_bounds__(256) void aggregate_full(const unsigned short* __restrict__ y,
                                                      const int* __restrict__ offs,
                                                      const int* __restrict__ deg,
                                                      const int* __restrict__ csr,
                                                      const float* __restrict__ dinv,
                                                      const float* __restrict__ bias,
                                                      const float* __restrict__ mask,
                                                      float* __restrict__ out) {
    int b = blockIdx.x & 7;
    int w = threadIdx.x >> 6;
    int idx = (blockIdx.x >> 3) * 4 + w;     // [0, 5000)
    int n0 = idx, n1 = idx + 5000;
    int lane = threadIdx.x & 63;
    const char* ybc = (const char*)(y + (size_t)b * NN * NH);   // wave-uniform base
    unsigned lane4 = (unsigned)lane * 4u;

    float2 acc0 = make_float2(0.f, 0.f);
    float2 acc1 = make_float2(0.f, 0.f);
    bf2_add(acc0, *(const unsigned*)(ybc + (unsigned)n0 * 256u + lane4));   // self-loop
    bf2_add(acc1, *(const unsigned*)(ybc + (unsigned)n1 * 256u + lane4));

    const int* ob = offs + b * NN;
    const int* db = deg + b * NN;
    int ba = ob[n0], o1a = ba + db[n0];
    int bb = ob[n1], o1b = bb + db[n1];

    while (ba < o1a || bb < o1b) {
        int ma = o1a - ba; ma = ma < 0 ? 0 : (ma > 64 ? 64 : ma);
        int mb = o1b - bb; mb = mb < 0 ? 0 : (mb > 64 ? 64 : mb);
        int ra = (lane < ma) ? csr[ba + lane] : 0;   // byte offsets
        int rb = (lane < mb) ? csr[bb + lane] : 0;
        int mmin = ma < mb ? ma : mb;
        int jj = 0;
#pragma unroll 4
        for (; jj < mmin; ++jj) {                    // two independent gather streams
            unsigned o0 = (unsigned)__shfl(ra, jj);
            unsigned o1 = (unsigned)__shfl(rb, jj);
            unsigned u0 = *(const unsigned*)(ybc + o0 + lane4);
            unsigned u1 = *(const unsigned*)(ybc + o1 + lane4);
            bf2_add(acc0, u0);
            bf2_add(acc1, u1);
        }
#pragma unroll 4
        for (; jj < ma; ++jj) {
            unsigned o0 = (unsigned)__shfl(ra, jj);
            bf2_add(acc0, *(const unsigned*)(ybc + o0 + lane4));
        }
#pragma unroll 4
        for (; jj < mb; ++jj) {
            unsigned o1 = (unsigned)__shfl(rb, jj);
            bf2_add(acc1, *(const unsigned*)(ybc + o1 + lane4));
        }
        ba += 64; bb += 64;
    }

    float2 bi = *(const float2*)(bias + lane * 2);
#pragma unroll
    for (int s2 = 0; s2 < 2; ++s2) {
        int n = s2 ? n1 : n0;
        float2 a = s2 ? acc1 : acc0;
        float d = dinv[b * NN + n];
        float2 o;
        o.x = fmaf(d, a.x, bi.x);
        o.y = fmaf(d, a.y, bi.y);
        if (LAYER == 1) {
            float2 m2 = *(const float2*)(mask + (size_t)n * NH + lane * 2);
            o.x = fmaxf(o.x, 0.f) * m2.x;
            o.y = fmaxf(o.y, 0.f) * m2.y;
        }
        *(float2*)(out + ((size_t)b * NN + n) * NH + lane * 2) = o;
    }
}

extern "C" void kernel_launch(void* const* d_in, const int* in_sizes, int n_in,
                              void* d_out, int out_size, void* d_ws, size_t ws_size,
                              hipStream_t stream) {
    const float* xs = (const float*)d_in[0];
    const int*   ei = (const int*)d_in[1];
    const float* W1 = (const float*)d_in[2];
    const float* b1 = (const float*)d_in[3];
    const float* W2 = (const float*)d_in[4];
    const float* b2 = (const float*)d_in[5];
    float* out = (float*)d_out;

    float* ws        = (float*)d_ws;
    float* dinv      = ws;
    int*   deg       = (int*)(ws + 80000);
    int*   flag      = (int*)(ws + 160000);
    float* mask      = ws + 160016;
    int*   offs      = (int*)(ws + 1440016);
    int*   gcur      = (int*)(ws + 1520016);
    unsigned* gbucket= (unsigned*)(ws + 1520272);
    int*   csr       = (int*)(ws + 4666000);
    unsigned short* y= (unsigned short*)(ws + 7811728);

    hipMemsetAsync(gcur, 0, NB * RNG * sizeof(int), stream);
    detect_kernel<<<1, 256, 0, stream>>>(ei, flag);
    mask_kernel<<<(NN * NH + 255) / 256, 256, 0, stream>>>(mask);
    part_kernel<<<8 * (NE / P1E), 256, 0, stream>>>(ei, flag, gcur, gbucket);
    build_kernel<<<NB * RNG, 512, 0, stream>>>(gbucket, gcur, csr, deg, offs);
    dinv_kernel<<<(NB * NN + 255) / 256, 256, 0, stream>>>(deg, dinv);

    dim3 gemm_grid(8 * ((NN + 63) / 64));   // blockIdx&7 = graph (XCD-local)
    dim3 agg_grid(NB * (5000 / 4));         // 10000 blocks, 4 waves x 2 nodes each

    // Layer 1: h -> d_out
    gemm_scale<<<gemm_grid, 256, 0, stream>>>(xs, W1, dinv, y);
    aggregate_full<1><<<agg_grid, 256, 0, stream>>>(y, offs, deg, csr, dinv, b1, mask, out);

    // Layer 2: reads h from d_out into y, then overwrites d_out
    gemm_scale<<<gemm_grid, 256, 0, stream>>>(out, W2, dinv, y);
    aggregate_full<2><<<agg_grid, 256, 0, stream>>>(y, offs, deg, csr, dinv, b2, nullptr, out);
}

// Round 13
// 263.534 us; speedup vs baseline: 2.6962x; 1.0668x over previous
//
#include <hip/hip_runtime.h>
#include <hip/hip_bf16.h>

#define NB 8
#define NN 10000
#define NE 320000
#define NF 128
#define NH 128
#define RNG 32            // node ranges (buckets) per graph
#define RS 313            // ceil(NN/RNG)
#define BCAP 12288        // per-bucket capacity; mean 10000, sigma ~98 -> +23 sigma
#define P1E 8000          // edges per pass-1 block
#define P1CAP 512         // pass-1 LDS slots per bucket; mean 250, sigma ~16

// ---------------- ws layout (float indices into ws) ----------------
// [0,        80000)     dinv    (NB*NN f32)
// [80000,   160000)     deg     (NB*NN i32)
// [160000,  160016)     flag    (i32 edge-dtype detect)
// [160016,  1440016)    mask    (NN*NH f32: 0.0 or 2.0)
// [1440016, 1520016)    offs    (NB*NN i32, ABSOLUTE index into csr)
// [1520016, 1520272)    gcur    (NB*RNG i32 bucket cursors)
// [1520272, 4666000)    gbucket (NB*RNG*BCAP u32 packed col<<14|row)
// [4666000, 7811728)    csr     (NB*RNG*BCAP i32 BYTE offsets row*256)
// [7811728, 10371728)   y       (NB*NN*NH bf16 = 20.5MB)

__device__ __forceinline__ int load_edge_nt(const int* ei, size_t idx, int is64) {
    if (is64) return (int)__builtin_nontemporal_load(((const long long*)ei) + idx);
    return __builtin_nontemporal_load(ei + idx);
}

__device__ __forceinline__ unsigned short f2bf(float x) {
    __hip_bfloat16 h = __float2bfloat16(x);   // RNE
    return *reinterpret_cast<unsigned short*>(&h);
}

// unpack uint2 = 4 bf16 (low ushort first) into float4 accumulator
__device__ __forceinline__ void bf4_add(float4& a, uint2 u) {
    union { unsigned q; float f; } t;
    t.q = u.x << 16;        a.x += t.f;
    t.q = u.x & 0xffff0000u; a.y += t.f;
    t.q = u.y << 16;        a.z += t.f;
    t.q = u.y & 0xffff0000u; a.w += t.f;
}

__global__ void detect_kernel(const int* __restrict__ ei, int* __restrict__ flag) {
    __shared__ int s;
    if (threadIdx.x == 0) s = 1;
    __syncthreads();
    int bad = 0;
    for (int q = threadIdx.x; q < 1024; q += 256)
        if (ei[2 * q + 1] != 0) bad = 1;
    if (bad) atomicAnd(&s, 0);
    __syncthreads();
    if (threadIdx.x == 0) *flag = s;   // 1 => int64 layout
}

// JAX threefry2x32, partitionable path: counter i -> (hi=0, lo=i), key (0,42),
// out = x0 ^ x1; keep <=> MSB==0; scale 2.0 (keep) else 0.0.
__global__ void mask_kernel(float* __restrict__ mask) {
    const unsigned TOT = NN * NH;
    unsigned i = blockIdx.x * 256 + threadIdx.x;
    if (i >= TOT) return;
    const unsigned ks0 = 0u, ks1 = 42u, ks2 = 0x1BD11BDAu ^ 0u ^ 42u;
    unsigned x0 = 0u + ks0;
    unsigned x1 = i + ks1;
#define TFR(r) { x0 += x1; x1 = (x1 << (r)) | (x1 >> (32 - (r))); x1 ^= x0; }
    TFR(13) TFR(15) TFR(26) TFR(6)
    x0 += ks1; x1 += ks2 + 1u;
    TFR(17) TFR(29) TFR(16) TFR(24)
    x0 += ks2; x1 += ks0 + 2u;
    TFR(13) TFR(15) TFR(26) TFR(6)
    x0 += ks0; x1 += ks1 + 3u;
    TFR(17) TFR(29) TFR(16) TFR(24)
    x0 += ks1; x1 += ks2 + 4u;
    TFR(13) TFR(15) TFR(26) TFR(6)
    x0 += ks2; x1 += ks0 + 5u;
#undef TFR
    unsigned bits = x0 ^ x1;
    mask[i] = (bits & 0x80000000u) ? 0.0f : 2.0f;
}

// Pass 1: read edges ONCE, bin into 32 node-range buckets in LDS, append each
// segment to the graph's global bucket region with coalesced ~1KB runs.
__global__ __launch_bounds__(256) void part_kernel(const int* __restrict__ ei,
                                                   const int* __restrict__ flag,
                                                   int* __restrict__ gcur,
                                                   unsigned* __restrict__ gbucket) {
    int b = blockIdx.x & 7;                       // graph (XCD-local)
    int chunk = blockIdx.x >> 3;                  // 0..39
    int e0 = chunk * P1E, e1 = e0 + P1E;
    __shared__ int bcnt[RNG];
    __shared__ unsigned bbuf[RNG][P1CAP];
    for (int i = threadIdx.x; i < RNG; i += 256) bcnt[i] = 0;
    __syncthreads();
    int is64 = *flag;
    size_t base = (size_t)b * 2 * NE;
    for (int e = e0 + threadIdx.x; e < e1; e += 256) {
        int row = load_edge_nt(ei, base + e, is64);
        int col = load_edge_nt(ei, base + NE + e, is64);
        int bk = col / RS;                        // magic-mul division
        unsigned pk = ((unsigned)col << 14) | (unsigned)row;
        int p = atomicAdd(&bcnt[bk], 1);
        if (p < P1CAP) bbuf[bk][p] = pk;
        else {                                    // statistically never
            int gp = atomicAdd(&gcur[b * RNG + bk], 1);
            if (gp < BCAP) gbucket[(size_t)(b * RNG + bk) * BCAP + gp] = pk;
        }
    }
    __syncthreads();
    int wave = threadIdx.x >> 6, lane = threadIdx.x & 63;
    for (int bk = wave; bk < RNG; bk += 4) {
        int len = bcnt[bk]; if (len > P1CAP) len = P1CAP;
        int gb = 0;
        if (lane == 0) gb = atomicAdd(&gcur[b * RNG + bk], len);
        gb = __shfl(gb, 0);
        unsigned* dst = gbucket + (size_t)(b * RNG + bk) * BCAP;
        for (int i = lane; i < len; i += 64)
            if (gb + i < BCAP) dst[gb + i] = bbuf[bk][i];
    }
}

// Pass 2: one block per (graph,range). Read bucket (~10K edges, L2-hot),
// LDS hist -> block scan -> LDS scatter -> coalesced csr copy-out.
// csr entries are PRE-SCALED BYTE OFFSETS (row*256).
__global__ __launch_bounds__(512) void build_kernel(const unsigned* __restrict__ gbucket,
                                                    const int* __restrict__ gcur,
                                                    int* __restrict__ csr,
                                                    int* __restrict__ deg,
                                                    int* __restrict__ offs) {
    int b = blockIdx.x & 7;
    int r = blockIdx.x >> 3;                      // 0..31
    int n0 = r * RS;
    int nloc = (NN - n0 < RS) ? (NN - n0) : RS;
    __shared__ int cnt[512];
    __shared__ int cur[RS];
    __shared__ int buf[BCAP];
    int gidx = b * RNG + r;
    int K = gcur[gidx]; if (K > BCAP) K = BCAP;
    const unsigned* src = gbucket + (size_t)gidx * BCAP;
    int t = threadIdx.x;
    cnt[t] = 0;
    __syncthreads();
    for (int i = t; i < K; i += 512)
        atomicAdd(&cnt[(src[i] >> 14) - n0], 1);
    __syncthreads();
    int v = cnt[t];
    __syncthreads();
    // Hillis-Steele inclusive scan over 512
    int x = v;
    cnt[t] = x;
    __syncthreads();
    for (int off = 1; off < 512; off <<= 1) {
        int add = (t >= off) ? cnt[t - off] : 0;
        __syncthreads();
        x += add;
        cnt[t] = x;
        __syncthreads();
    }
    int excl = x - v;
    if (t < nloc) {
        deg[b * NN + n0 + t] = v;
        offs[b * NN + n0 + t] = gidx * BCAP + excl;   // absolute into csr
        cur[t] = excl;
    }
    __syncthreads();
    for (int i = t; i < K; i += 512) {
        unsigned pk = src[i];
        int p = atomicAdd(&cur[(pk >> 14) - n0], 1);
        buf[p] = (int)((pk & 16383u) << 8);           // row*256 byte offset
    }
    __syncthreads();
    int* dstc = csr + (size_t)gidx * BCAP;
    for (int i = t; i < K; i += 512) dstc[i] = buf[i];   // coalesced
}

__global__ __launch_bounds__(256) void dinv_kernel(const int* __restrict__ deg,
                                                   float* __restrict__ dinv) {
    int i = blockIdx.x * 256 + threadIdx.x;
    if (i >= NB * NN) return;
    dinv[i] = 1.0f / sqrtf((float)(deg[i] + 1));  // +1 self-loop
}

// y = bf16[(X @ W) * dinv[row]].  blockIdx.x&7 = graph (XCD-local).
__global__ __launch_bounds__(256) void gemm_scale(const float* __restrict__ X,
                                                  const float* __restrict__ Wm,
                                                  const float* __restrict__ dinv,
                                                  unsigned short* __restrict__ y) {
    __shared__ float Xs[64][32];
    __shared__ float Ws[32][128];
    int b = blockIdx.x & 7;
    int row0 = (blockIdx.x >> 3) * 64;
    int t = threadIdx.x;
    int cg = t & 31;
    int rg = t >> 5;
    float acc[8][4] = {};
    const float* Xb = X + (size_t)b * NN * NF;

    for (int k0 = 0; k0 < NF; k0 += 32) {
        for (int q = t; q < 512; q += 256) {
            int r = q >> 3, c4 = q & 7;
            int gr = row0 + r;
            float4 v = make_float4(0.f, 0.f, 0.f, 0.f);
            if (gr < NN) v = *(const float4*)(Xb + (size_t)gr * NF + k0 + c4 * 4);
            *(float4*)&Xs[r][c4 * 4] = v;
        }
        for (int q = t; q < 1024; q += 256) {
            float4 v = *(const float4*)(Wm + k0 * NH + q * 4);
            *(float4*)(&Ws[0][0] + q * 4) = v;
        }
        __syncthreads();
#pragma unroll
        for (int kc = 0; kc < 32; kc += 4) {
            float4 xv[8];
#pragma unroll
            for (int i = 0; i < 8; ++i) xv[i] = *(const float4*)&Xs[rg * 8 + i][kc];
#pragma unroll
            for (int j = 0; j < 4; ++j) {
                float4 w = *(const float4*)&Ws[kc + j][cg * 4];
#pragma unroll
                for (int i = 0; i < 8; ++i) {
                    float xsv = (j == 0) ? xv[i].x : (j == 1) ? xv[i].y
                              : (j == 2) ? xv[i].z : xv[i].w;
                    acc[i][0] = fmaf(xsv, w.x, acc[i][0]);
                    acc[i][1] = fmaf(xsv, w.y, acc[i][1]);
                    acc[i][2] = fmaf(xsv, w.z, acc[i][2]);
                    acc[i][3] = fmaf(xsv, w.w, acc[i][3]);
                }
            }
        }
        __syncthreads();
    }
#pragma unroll
    for (int i = 0; i < 8; ++i) {
        int gr = row0 + rg * 8 + i;
        if (gr >= NN) continue;
        float d = dinv[b * NN + gr];
        ushort4 u;
        u.x = f2bf(acc[i][0] * d);
        u.y = f2bf(acc[i][1] * d);
        u.z = f2bf(acc[i][2] * d);
        u.w = f2bf(acc[i][3] * d);
        *(ushort4*)(y + ((size_t)b * NN + gr) * NH + cg * 4) = u;
    }
}

// Gather-reduce. r12 profile: L2-MLP bound (VALUBusy 42%, dur flat when VALU
// cut). Restructure: each edge-row (256B) read by a HALF-wave (32 lanes x 8B
// dwordx2); wave-halves process DIFFERENT edges (one load = 2 edges = 512B).
// 2 node-streams x 2 edges = 4 edges in flight per loop body, 2x bytes per
// vmcnt slot. shfl_xor(32) merges halves; half 0 writes n0, half 1 writes n1.
template<int LAYER>
__global__ __launch_bounds__(256) void aggregate_full(const unsigned short* __restrict__ y,
                                                      const int* __restrict__ offs,
                                                      const int* __restrict__ deg,
                                                      const int* __restrict__ csr,
                                                      const float* __restrict__ dinv,
                                                      const float* __restrict__ bias,
                                                      const float* __restrict__ mask,
                                                      float* __restrict__ out) {
    int b = blockIdx.x & 7;
    int w = threadIdx.x >> 6;
    int idx = (blockIdx.x >> 3) * 4 + w;     // [0, 5000)
    int n0 = idx, n1 = idx + 5000;
    int lane = threadIdx.x & 63;
    int half = lane >> 5;                    // which edge of a pair
    unsigned hlane8 = (unsigned)(lane & 31) * 8u;   // byte offset of feat quad
    const char* ybc = (const char*)(y + (size_t)b * NN * NH);   // wave-uniform base

    float4 acc0 = make_float4(0.f, 0.f, 0.f, 0.f);
    float4 acc1 = make_float4(0.f, 0.f, 0.f, 0.f);
    {   // self-loop: same address for both halves; add in half 0 only
        uint2 s0 = *(const uint2*)(ybc + (unsigned)n0 * 256u + hlane8);
        uint2 s1 = *(const uint2*)(ybc + (unsigned)n1 * 256u + hlane8);
        if (half == 0) { bf4_add(acc0, s0); bf4_add(acc1, s1); }
    }

    const int* ob = offs + b * NN;
    const int* db = deg + b * NN;
    int ba = ob[n0], o1a = ba + db[n0];
    int bb = ob[n1], o1b = bb + db[n1];

#define PROC2(r_, j_, acc_) { \
    unsigned o = (unsigned)__shfl((r_), (j_) + half); \
    uint2 u = *(const uint2*)(ybc + o + hlane8); \
    bf4_add(acc_, u); \
}
#define PROC1(r_, j_, acc_) { \
    unsigned o = (unsigned)__shfl((r_), (j_)); \
    if (half == 0) { \
        uint2 u = *(const uint2*)(ybc + o + hlane8); \
        bf4_add(acc_, u); \
    } \
}

    while (ba < o1a || bb < o1b) {
        int ma = o1a - ba; ma = ma < 0 ? 0 : (ma > 64 ? 64 : ma);
        int mb = o1b - bb; mb = mb < 0 ? 0 : (mb > 64 ? 64 : mb);
        int ra = (lane < ma) ? csr[ba + lane] : 0;   // byte offsets
        int rb = (lane < mb) ? csr[bb + lane] : 0;
        int mmin = ma < mb ? ma : mb;
        int jj = 0;
#pragma unroll 4
        for (; jj + 1 < mmin; jj += 2) {             // 4 edges in flight
            PROC2(ra, jj, acc0)
            PROC2(rb, jj, acc1)
        }
        int ja = jj, jb = jj;
#pragma unroll 2
        for (; ja + 1 < ma; ja += 2) PROC2(ra, ja, acc0)
        if (ja < ma) PROC1(ra, ja, acc0)
#pragma unroll 2
        for (; jb + 1 < mb; jb += 2) PROC2(rb, jb, acc1)
        if (jb < mb) PROC1(rb, jb, acc1)
        ba += 64; bb += 64;
    }
#undef PROC2
#undef PROC1

    // merge the two edge-halves (lanes L and L+32 hold same feats)
    acc0.x += __shfl_xor(acc0.x, 32); acc0.y += __shfl_xor(acc0.y, 32);
    acc0.z += __shfl_xor(acc0.z, 32); acc0.w += __shfl_xor(acc0.w, 32);
    acc1.x += __shfl_xor(acc1.x, 32); acc1.y += __shfl_xor(acc1.y, 32);
    acc1.z += __shfl_xor(acc1.z, 32); acc1.w += __shfl_xor(acc1.w, 32);

    // half 0 writes n0, half 1 writes n1 (each: 32 lanes x 16B contiguous)
    int n = half ? n1 : n0;
    float4 a = half ? acc1 : acc0;
    float d = dinv[b * NN + n];
    unsigned f0 = (lane & 31) * 4;               // feature index of quad
    float4 bi = *(const float4*)(bias + f0);
    float4 o;
    o.x = fmaf(d, a.x, bi.x);
    o.y = fmaf(d, a.y, bi.y);
    o.z = fmaf(d, a.z, bi.z);
    o.w = fmaf(d, a.w, bi.w);
    if (LAYER == 1) {
        float4 m4 = *(const float4*)(mask + (size_t)n * NH + f0);
        o.x = fmaxf(o.x, 0.f) * m4.x;
        o.y = fmaxf(o.y, 0.f) * m4.y;
        o.z = fmaxf(o.z, 0.f) * m4.z;
        o.w = fmaxf(o.w, 0.f) * m4.w;
    }
    *(float4*)(out + ((size_t)b * NN + n) * NH + f0) = o;
}

extern "C" void kernel_launch(void* const* d_in, const int* in_sizes, int n_in,
                              void* d_out, int out_size, void* d_ws, size_t ws_size,
                              hipStream_t stream) {
    const float* xs = (const float*)d_in[0];
    const int*   ei = (const int*)d_in[1];
    const float* W1 = (const float*)d_in[2];
    const float* b1 = (const float*)d_in[3];
    const float* W2 = (const float*)d_in[4];
    const float* b2 = (const float*)d_in[5];
    float* out = (float*)d_out;

    float* ws        = (float*)d_ws;
    float* dinv      = ws;
    int*   deg       = (int*)(ws + 80000);
    int*   flag      = (int*)(ws + 160000);
    float* mask      = ws + 160016;
    int*   offs      = (int*)(ws + 1440016);
    int*   gcur      = (int*)(ws + 1520016);
    unsigned* gbucket= (unsigned*)(ws + 1520272);
    int*   csr       = (int*)(ws + 4666000);
    unsigned short* y= (unsigned short*)(ws + 7811728);

    hipMemsetAsync(gcur, 0, NB * RNG * sizeof(int), stream);
    detect_kernel<<<1, 256, 0, stream>>>(ei, flag);
    mask_kernel<<<(NN * NH + 255) / 256, 256, 0, stream>>>(mask);
    part_kernel<<<8 * (NE / P1E), 256, 0, stream>>>(ei, flag, gcur, gbucket);
    build_kernel<<<NB * RNG, 512, 0, stream>>>(gbucket, gcur, csr, deg, offs);
    dinv_kernel<<<(NB * NN + 255) / 256, 256, 0, stream>>>(deg, dinv);

    dim3 gemm_grid(8 * ((NN + 63) / 64));   // blockIdx&7 = graph (XCD-local)
    dim3 agg_grid(NB * (5000 / 4));         // 10000 blocks, 4 waves x 2 nodes each

    // Layer 1: h -> d_out
    gemm_scale<<<gemm_grid, 256, 0, stream>>>(xs, W1, dinv, y);
    aggregate_full<1><<<agg_grid, 256, 0, stream>>>(y, offs, deg, csr, dinv, b1, mask, out);

    // Layer 2: reads h from d_out into y, then overwrites d_out
    gemm_scale<<<gemm_grid, 256, 0, stream>>>(out, W2, dinv, y);
    aggregate_full<2><<<agg_grid, 256, 0, stream>>>(y, offs, deg, csr, dinv, b2, nullptr, out);
}

// Round 14
// 246.048 us; speedup vs baseline: 2.8878x; 1.0711x over previous
//
#include <hip/hip_runtime.h>
#include <hip/hip_bf16.h>

#define NB 8
#define NN 10000
#define NE 320000
#define NF 128
#define NH 128
#define RNG 32            // node ranges (buckets) per graph
#define RS 313            // ceil(NN/RNG)
#define BCAP 12288        // per-bucket capacity; mean 10000, sigma ~98 -> +23 sigma
#define P1E 8000          // edges per pass-1 block
#define P1CAP 512         // pass-1 LDS slots per bucket; mean 250, sigma ~16

// ---------------- ws layout (float indices into ws) ----------------
// [0,        80000)     dinv    (NB*NN f32)
// [80000,   160000)     deg     (NB*NN i32)
// [160000,  160016)     flag    (i32 edge-dtype detect)
// [160016,  1440016)    mask    (NN*NH f32: 0.0 or 2.0)
// [1440016, 1520016)    offs    (NB*NN i32, ABSOLUTE index into csr)
// [1520016, 1520272)    gcur    (NB*RNG i32 bucket cursors)
// [1520272, 4666000)    gbucket (NB*RNG*BCAP u32 packed col<<14|row)
// [4666000, 7811728)    csr     (NB*RNG*BCAP i32 BYTE offsets row*256)
// [7811728, 10371728)   y       (NB*NN*NH bf16 = 20.5MB)

__device__ __forceinline__ int load_edge_nt(const int* ei, size_t idx, int is64) {
    if (is64) return (int)__builtin_nontemporal_load(((const long long*)ei) + idx);
    return __builtin_nontemporal_load(ei + idx);
}

__device__ __forceinline__ unsigned short f2bf(float x) {
    __hip_bfloat16 h = __float2bfloat16(x);   // RNE
    return *reinterpret_cast<unsigned short*>(&h);
}

// unpack uint4 = 8 bf16 (low ushort first) into 8-float accumulator
__device__ __forceinline__ void bf8_add(float* a, uint4 u) {
    union { unsigned q; float f; } t;
    t.q = u.x << 16;         a[0] += t.f;
    t.q = u.x & 0xffff0000u; a[1] += t.f;
    t.q = u.y << 16;         a[2] += t.f;
    t.q = u.y & 0xffff0000u; a[3] += t.f;
    t.q = u.z << 16;         a[4] += t.f;
    t.q = u.z & 0xffff0000u; a[5] += t.f;
    t.q = u.w << 16;         a[6] += t.f;
    t.q = u.w & 0xffff0000u; a[7] += t.f;
}

__global__ void detect_kernel(const int* __restrict__ ei, int* __restrict__ flag) {
    __shared__ int s;
    if (threadIdx.x == 0) s = 1;
    __syncthreads();
    int bad = 0;
    for (int q = threadIdx.x; q < 1024; q += 256)
        if (ei[2 * q + 1] != 0) bad = 1;
    if (bad) atomicAnd(&s, 0);
    __syncthreads();
    if (threadIdx.x == 0) *flag = s;   // 1 => int64 layout
}

// JAX threefry2x32, partitionable path: counter i -> (hi=0, lo=i), key (0,42),
// out = x0 ^ x1; keep <=> MSB==0; scale 2.0 (keep) else 0.0.
__global__ void mask_kernel(float* __restrict__ mask) {
    const unsigned TOT = NN * NH;
    unsigned i = blockIdx.x * 256 + threadIdx.x;
    if (i >= TOT) return;
    const unsigned ks0 = 0u, ks1 = 42u, ks2 = 0x1BD11BDAu ^ 0u ^ 42u;
    unsigned x0 = 0u + ks0;
    unsigned x1 = i + ks1;
#define TFR(r) { x0 += x1; x1 = (x1 << (r)) | (x1 >> (32 - (r))); x1 ^= x0; }
    TFR(13) TFR(15) TFR(26) TFR(6)
    x0 += ks1; x1 += ks2 + 1u;
    TFR(17) TFR(29) TFR(16) TFR(24)
    x0 += ks2; x1 += ks0 + 2u;
    TFR(13) TFR(15) TFR(26) TFR(6)
    x0 += ks0; x1 += ks1 + 3u;
    TFR(17) TFR(29) TFR(16) TFR(24)
    x0 += ks1; x1 += ks2 + 4u;
    TFR(13) TFR(15) TFR(26) TFR(6)
    x0 += ks2; x1 += ks0 + 5u;
#undef TFR
    unsigned bits = x0 ^ x1;
    mask[i] = (bits & 0x80000000u) ? 0.0f : 2.0f;
}

// Pass 1: read edges ONCE, bin into 32 node-range buckets in LDS, append each
// segment to the graph's global bucket region with coalesced ~1KB runs.
__global__ __launch_bounds__(256) void part_kernel(const int* __restrict__ ei,
                                                   const int* __restrict__ flag,
                                                   int* __restrict__ gcur,
                                                   unsigned* __restrict__ gbucket) {
    int b = blockIdx.x & 7;                       // graph (XCD-local)
    int chunk = blockIdx.x >> 3;                  // 0..39
    int e0 = chunk * P1E, e1 = e0 + P1E;
    __shared__ int bcnt[RNG];
    __shared__ unsigned bbuf[RNG][P1CAP];
    for (int i = threadIdx.x; i < RNG; i += 256) bcnt[i] = 0;
    __syncthreads();
    int is64 = *flag;
    size_t base = (size_t)b * 2 * NE;
    for (int e = e0 + threadIdx.x; e < e1; e += 256) {
        int row = load_edge_nt(ei, base + e, is64);
        int col = load_edge_nt(ei, base + NE + e, is64);
        int bk = col / RS;                        // magic-mul division
        unsigned pk = ((unsigned)col << 14) | (unsigned)row;
        int p = atomicAdd(&bcnt[bk], 1);
        if (p < P1CAP) bbuf[bk][p] = pk;
        else {                                    // statistically never
            int gp = atomicAdd(&gcur[b * RNG + bk], 1);
            if (gp < BCAP) gbucket[(size_t)(b * RNG + bk) * BCAP + gp] = pk;
        }
    }
    __syncthreads();
    int wave = threadIdx.x >> 6, lane = threadIdx.x & 63;
    for (int bk = wave; bk < RNG; bk += 4) {
        int len = bcnt[bk]; if (len > P1CAP) len = P1CAP;
        int gb = 0;
        if (lane == 0) gb = atomicAdd(&gcur[b * RNG + bk], len);
        gb = __shfl(gb, 0);
        unsigned* dst = gbucket + (size_t)(b * RNG + bk) * BCAP;
        for (int i = lane; i < len; i += 64)
            if (gb + i < BCAP) dst[gb + i] = bbuf[bk][i];
    }
}

// Pass 2: one block per (graph,range). Read bucket (~10K edges, L2-hot),
// LDS hist -> block scan -> LDS scatter -> coalesced csr copy-out.
// csr entries are PRE-SCALED BYTE OFFSETS (row*256).
__global__ __launch_bounds__(512) void build_kernel(const unsigned* __restrict__ gbucket,
                                                    const int* __restrict__ gcur,
                                                    int* __restrict__ csr,
                                                    int* __restrict__ deg,
                                                    int* __restrict__ offs) {
    int b = blockIdx.x & 7;
    int r = blockIdx.x >> 3;                      // 0..31
    int n0 = r * RS;
    int nloc = (NN - n0 < RS) ? (NN - n0) : RS;
    __shared__ int cnt[512];
    __shared__ int cur[RS];
    __shared__ int buf[BCAP];
    int gidx = b * RNG + r;
    int K = gcur[gidx]; if (K > BCAP) K = BCAP;
    const unsigned* src = gbucket + (size_t)gidx * BCAP;
    int t = threadIdx.x;
    cnt[t] = 0;
    __syncthreads();
    for (int i = t; i < K; i += 512)
        atomicAdd(&cnt[(src[i] >> 14) - n0], 1);
    __syncthreads();
    int v = cnt[t];
    __syncthreads();
    // Hillis-Steele inclusive scan over 512
    int x = v;
    cnt[t] = x;
    __syncthreads();
    for (int off = 1; off < 512; off <<= 1) {
        int add = (t >= off) ? cnt[t - off] : 0;
        __syncthreads();
        x += add;
        cnt[t] = x;
        __syncthreads();
    }
    int excl = x - v;
    if (t < nloc) {
        deg[b * NN + n0 + t] = v;
        offs[b * NN + n0 + t] = gidx * BCAP + excl;   // absolute into csr
        cur[t] = excl;
    }
    __syncthreads();
    for (int i = t; i < K; i += 512) {
        unsigned pk = src[i];
        int p = atomicAdd(&cur[(pk >> 14) - n0], 1);
        buf[p] = (int)((pk & 16383u) << 8);           // row*256 byte offset
    }
    __syncthreads();
    int* dstc = csr + (size_t)gidx * BCAP;
    for (int i = t; i < K; i += 512) dstc[i] = buf[i];   // coalesced
}

__global__ __launch_bounds__(256) void dinv_kernel(const int* __restrict__ deg,
                                                   float* __restrict__ dinv) {
    int i = blockIdx.x * 256 + threadIdx.x;
    if (i >= NB * NN) return;
    dinv[i] = 1.0f / sqrtf((float)(deg[i] + 1));  // +1 self-loop
}

// y = bf16[(X @ W) * dinv[row]].  blockIdx.x&7 = graph (XCD-local).
__global__ __launch_bounds__(256) void gemm_scale(const float* __restrict__ X,
                                                  const float* __restrict__ Wm,
                                                  const float* __restrict__ dinv,
                                                  unsigned short* __restrict__ y) {
    __shared__ float Xs[64][32];
    __shared__ float Ws[32][128];
    int b = blockIdx.x & 7;
    int row0 = (blockIdx.x >> 3) * 64;
    int t = threadIdx.x;
    int cg = t & 31;
    int rg = t >> 5;
    float acc[8][4] = {};
    const float* Xb = X + (size_t)b * NN * NF;

    for (int k0 = 0; k0 < NF; k0 += 32) {
        for (int q = t; q < 512; q += 256) {
            int r = q >> 3, c4 = q & 7;
            int gr = row0 + r;
            float4 v = make_float4(0.f, 0.f, 0.f, 0.f);
            if (gr < NN) v = *(const float4*)(Xb + (size_t)gr * NF + k0 + c4 * 4);
            *(float4*)&Xs[r][c4 * 4] = v;
        }
        for (int q = t; q < 1024; q += 256) {
            float4 v = *(const float4*)(Wm + k0 * NH + q * 4);
            *(float4*)(&Ws[0][0] + q * 4) = v;
        }
        __syncthreads();
#pragma unroll
        for (int kc = 0; kc < 32; kc += 4) {
            float4 xv[8];
#pragma unroll
            for (int i = 0; i < 8; ++i) xv[i] = *(const float4*)&Xs[rg * 8 + i][kc];
#pragma unroll
            for (int j = 0; j < 4; ++j) {
                float4 w = *(const float4*)&Ws[kc + j][cg * 4];
#pragma unroll
                for (int i = 0; i < 8; ++i) {
                    float xsv = (j == 0) ? xv[i].x : (j == 1) ? xv[i].y
                              : (j == 2) ? xv[i].z : xv[i].w;
                    acc[i][0] = fmaf(xsv, w.x, acc[i][0]);
                    acc[i][1] = fmaf(xsv, w.y, acc[i][1]);
                    acc[i][2] = fmaf(xsv, w.z, acc[i][2]);
                    acc[i][3] = fmaf(xsv, w.w, acc[i][3]);
                }
            }
        }
        __syncthreads();
    }
#pragma unroll
    for (int i = 0; i < 8; ++i) {
        int gr = row0 + rg * 8 + i;
        if (gr >= NN) continue;
        float d = dinv[b * NN + gr];
        ushort4 u;
        u.x = f2bf(acc[i][0] * d);
        u.y = f2bf(acc[i][1] * d);
        u.z = f2bf(acc[i][2] * d);
        u.w = f2bf(acc[i][3] * d);
        *(ushort4*)(y + ((size_t)b * NN + gr) * NH + cg * 4) = u;
    }
}

// Gather-reduce, quarter-wave form. r12/r13 established: L2-MLP bound; gain
// tracks bytes-per-outstanding-load. Each edge-row (256B) read by a QUARTER
// wave (16 lanes x dwordx4); quarters process 4 DIFFERENT edges -> one load
// instruction = 4 edges = 1024B in flight. 2 node-streams x 4 edges = 8 edges
// per loop body. Merge via shfl_xor(16,32); self-loop in quarter 0 only;
// epilogue: quarter 0 writes n0, quarter 1 writes n1.
template<int LAYER>
__global__ __launch_bounds__(256) void aggregate_full(const unsigned short* __restrict__ y,
                                                      const int* __restrict__ offs,
                                                      const int* __restrict__ deg,
                                                      const int* __restrict__ csr,
                                                      const float* __restrict__ dinv,
                                                      const float* __restrict__ bias,
                                                      const float* __restrict__ mask,
                                                      float* __restrict__ out) {
    int b = blockIdx.x & 7;
    int w = threadIdx.x >> 6;
    int idx = (blockIdx.x >> 3) * 4 + w;     // [0, 5000)
    int n0 = idx, n1 = idx + 5000;
    int lane = threadIdx.x & 63;
    int q = lane >> 4;                       // quarter: which edge of a group of 4
    unsigned q16 = (unsigned)(lane & 15) * 16u;     // byte offset of feat octet
    const char* ybc = (const char*)(y + (size_t)b * NN * NH);   // wave-uniform base

    float a0[8] = {0.f,0.f,0.f,0.f,0.f,0.f,0.f,0.f};
    float a1[8] = {0.f,0.f,0.f,0.f,0.f,0.f,0.f,0.f};
    if (q == 0) {   // self-loop, counted once
        uint4 s0 = *(const uint4*)(ybc + (unsigned)n0 * 256u + q16);
        uint4 s1 = *(const uint4*)(ybc + (unsigned)n1 * 256u + q16);
        bf8_add(a0, s0);
        bf8_add(a1, s1);
    }

    const int* ob = offs + b * NN;
    const int* db = deg + b * NN;
    int ba = ob[n0], o1a = ba + db[n0];
    int bb = ob[n1], o1b = bb + db[n1];

#define PROCQ(r_, j_, acc_) { \
    unsigned o = (unsigned)__shfl((r_), (j_) + q); \
    uint4 u = *(const uint4*)(ybc + o + q16); \
    bf8_add(acc_, u); \
}
#define PROCT(r_, j_, rem_, acc_) { \
    unsigned o = (unsigned)__shfl((r_), (j_) + (q < (rem_) ? q : 0)); \
    uint4 u = *(const uint4*)(ybc + o + q16); \
    if (q < (rem_)) bf8_add(acc_, u); \
}

    while (ba < o1a || bb < o1b) {
        int ma = o1a - ba; ma = ma < 0 ? 0 : (ma > 64 ? 64 : ma);
        int mb = o1b - bb; mb = mb < 0 ? 0 : (mb > 64 ? 64 : mb);
        int ra = (lane < ma) ? csr[ba + lane] : 0;   // byte offsets
        int rb = (lane < mb) ? csr[bb + lane] : 0;
        int mmin = ma < mb ? ma : mb;
        int jj = 0;
#pragma unroll 2
        for (; jj + 3 < mmin; jj += 4) {             // 8 edges in flight
            PROCQ(ra, jj, a0)
            PROCQ(rb, jj, a1)
        }
        int ja = jj, jb = jj;
#pragma unroll 2
        for (; ja + 3 < ma; ja += 4) PROCQ(ra, ja, a0)
        if (ja < ma) PROCT(ra, ja, ma - ja, a0)
#pragma unroll 2
        for (; jb + 3 < mb; jb += 4) PROCQ(rb, jb, a1)
        if (jb < mb) PROCT(rb, jb, mb - jb, a1)
        ba += 64; bb += 64;
    }
#undef PROCQ
#undef PROCT

    // merge the 4 edge-quarters (lanes with equal lane&15 hold same feats)
#pragma unroll
    for (int i = 0; i < 8; ++i) {
        a0[i] += __shfl_xor(a0[i], 16);
        a0[i] += __shfl_xor(a0[i], 32);
        a1[i] += __shfl_xor(a1[i], 16);
        a1[i] += __shfl_xor(a1[i], 32);
    }

    // quarter 0 writes n0, quarter 1 writes n1 (16 lanes x 32B contiguous)
    if (q < 2) {
        int n = q ? n1 : n0;
        float av[8];
#pragma unroll
        for (int i = 0; i < 8; ++i) av[i] = q ? a1[i] : a0[i];
        float d = dinv[b * NN + n];
        unsigned f0 = (lane & 15) * 8;           // first feature of octet
        float4 bi0 = *(const float4*)(bias + f0);
        float4 bi1 = *(const float4*)(bias + f0 + 4);
        float4 o0, o1;
        o0.x = fmaf(d, av[0], bi0.x);
        o0.y = fmaf(d, av[1], bi0.y);
        o0.z = fmaf(d, av[2], bi0.z);
        o0.w = fmaf(d, av[3], bi0.w);
        o1.x = fmaf(d, av[4], bi1.x);
        o1.y = fmaf(d, av[5], bi1.y);
        o1.z = fmaf(d, av[6], bi1.z);
        o1.w = fmaf(d, av[7], bi1.w);
        if (LAYER == 1) {
            float4 m0 = *(const float4*)(mask + (size_t)n * NH + f0);
            float4 m1 = *(const float4*)(mask + (size_t)n * NH + f0 + 4);
            o0.x = fmaxf(o0.x, 0.f) * m0.x;
            o0.y = fmaxf(o0.y, 0.f) * m0.y;
            o0.z = fmaxf(o0.z, 0.f) * m0.z;
            o0.w = fmaxf(o0.w, 0.f) * m0.w;
            o1.x = fmaxf(o1.x, 0.f) * m1.x;
            o1.y = fmaxf(o1.y, 0.f) * m1.y;
            o1.z = fmaxf(o1.z, 0.f) * m1.z;
            o1.w = fmaxf(o1.w, 0.f) * m1.w;
        }
        float* op = out + ((size_t)b * NN + n) * NH + f0;
        *(float4*)op = o0;
        *(float4*)(op + 4) = o1;
    }
}

extern "C" void kernel_launch(void* const* d_in, const int* in_sizes, int n_in,
                              void* d_out, int out_size, void* d_ws, size_t ws_size,
                              hipStream_t stream) {
    const float* xs = (const float*)d_in[0];
    const int*   ei = (const int*)d_in[1];
    const float* W1 = (const float*)d_in[2];
    const float* b1 = (const float*)d_in[3];
    const float* W2 = (const float*)d_in[4];
    const float* b2 = (const float*)d_in[5];
    float* out = (float*)d_out;

    float* ws        = (float*)d_ws;
    float* dinv      = ws;
    int*   deg       = (int*)(ws + 80000);
    int*   flag      = (int*)(ws + 160000);
    float* mask      = ws + 160016;
    int*   offs      = (int*)(ws + 1440016);
    int*   gcur      = (int*)(ws + 1520016);
    unsigned* gbucket= (unsigned*)(ws + 1520272);
    int*   csr       = (int*)(ws + 4666000);
    unsigned short* y= (unsigned short*)(ws + 7811728);

    hipMemsetAsync(gcur, 0, NB * RNG * sizeof(int), stream);
    detect_kernel<<<1, 256, 0, stream>>>(ei, flag);
    mask_kernel<<<(NN * NH + 255) / 256, 256, 0, stream>>>(mask);
    part_kernel<<<8 * (NE / P1E), 256, 0, stream>>>(ei, flag, gcur, gbucket);
    build_kernel<<<NB * RNG, 512, 0, stream>>>(gbucket, gcur, csr, deg, offs);
    dinv_kernel<<<(NB * NN + 255) / 256, 256, 0, stream>>>(deg, dinv);

    dim3 gemm_grid(8 * ((NN + 63) / 64));   // blockIdx&7 = graph (XCD-local)
    dim3 agg_grid(NB * (5000 / 4));         // 10000 blocks, 4 waves x 2 nodes each

    // Layer 1: h -> d_out
    gemm_scale<<<gemm_grid, 256, 0, stream>>>(xs, W1, dinv, y);
    aggregate_full<1><<<agg_grid, 256, 0, stream>>>(y, offs, deg, csr, dinv, b1, mask, out);

    // Layer 2: reads h from d_out into y, then overwrites d_out
    gemm_scale<<<gemm_grid, 256, 0, stream>>>(out, W2, dinv, y);
    aggregate_full<2><<<agg_grid, 256, 0, stream>>>(y, offs, deg, csr, dinv, b2, nullptr, out);
}

// Round 15
// 209.345 us; speedup vs baseline: 3.3941x; 1.1753x over previous
//
#include <hip/hip_runtime.h>
#include <hip/hip_bf16.h>

#define NB 8
#define NN 10000
#define NE 320000
#define NF 128
#define NH 128
#define RNG 32            // node ranges (buckets) per graph
#define RS 313            // ceil(NN/RNG)
#define BCAP 12288        // per-bucket capacity; mean 10000, sigma ~98 -> +23 sigma
#define P1E 8000          // edges per pass-1 block
#define P1CAP 512         // pass-1 LDS slots per bucket; mean 250, sigma ~16

typedef __attribute__((ext_vector_type(8))) _Float16 half8;
typedef __attribute__((ext_vector_type(4))) float f32x4;

// ---------------- ws layout (float indices into ws) ----------------
// [0,        80000)     dinv    (NB*NN f32)
// [80000,   160000)     deg     (NB*NN i32)
// [160000,  160016)     flag    (i32 edge-dtype detect)
// [160016,  1440016)    mask    (NN*NH f32: 0.0 or 2.0)
// [1440016, 1520016)    offs    (NB*NN i32, ABSOLUTE index into csr)
// [1520016, 1520272)    gcur    (NB*RNG i32 bucket cursors)
// [1520272, 4666000)    gbucket (NB*RNG*BCAP u32 packed col<<14|row)
// [4666000, 7811728)    csr     (NB*RNG*BCAP i32 BYTE offsets row*256)
// [7811728, 10371728)   y       (NB*NN*NH bf16 = 20.5MB)

__device__ __forceinline__ int load_edge_nt(const int* ei, size_t idx, int is64) {
    if (is64) return (int)__builtin_nontemporal_load(((const long long*)ei) + idx);
    return __builtin_nontemporal_load(ei + idx);
}

__device__ __forceinline__ unsigned short f2bf(float x) {
    __hip_bfloat16 h = __float2bfloat16(x);   // RNE
    return *reinterpret_cast<unsigned short*>(&h);
}

// unpack uint4 = 8 bf16 (low ushort first) into 8-float accumulator
__device__ __forceinline__ void bf8_add(float* a, uint4 u) {
    union { unsigned q; float f; } t;
    t.q = u.x << 16;         a[0] += t.f;
    t.q = u.x & 0xffff0000u; a[1] += t.f;
    t.q = u.y << 16;         a[2] += t.f;
    t.q = u.y & 0xffff0000u; a[3] += t.f;
    t.q = u.z << 16;         a[4] += t.f;
    t.q = u.z & 0xffff0000u; a[5] += t.f;
    t.q = u.w << 16;         a[6] += t.f;
    t.q = u.w & 0xffff0000u; a[7] += t.f;
}

__global__ void detect_kernel(const int* __restrict__ ei, int* __restrict__ flag) {
    __shared__ int s;
    if (threadIdx.x == 0) s = 1;
    __syncthreads();
    int bad = 0;
    for (int q = threadIdx.x; q < 1024; q += 256)
        if (ei[2 * q + 1] != 0) bad = 1;
    if (bad) atomicAnd(&s, 0);
    __syncthreads();
    if (threadIdx.x == 0) *flag = s;   // 1 => int64 layout
}

// JAX threefry2x32, partitionable path: counter i -> (hi=0, lo=i), key (0,42),
// out = x0 ^ x1; keep <=> MSB==0; scale 2.0 (keep) else 0.0.
__global__ void mask_kernel(float* __restrict__ mask) {
    const unsigned TOT = NN * NH;
    unsigned i = blockIdx.x * 256 + threadIdx.x;
    if (i >= TOT) return;
    const unsigned ks0 = 0u, ks1 = 42u, ks2 = 0x1BD11BDAu ^ 0u ^ 42u;
    unsigned x0 = 0u + ks0;
    unsigned x1 = i + ks1;
#define TFR(r) { x0 += x1; x1 = (x1 << (r)) | (x1 >> (32 - (r))); x1 ^= x0; }
    TFR(13) TFR(15) TFR(26) TFR(6)
    x0 += ks1; x1 += ks2 + 1u;
    TFR(17) TFR(29) TFR(16) TFR(24)
    x0 += ks2; x1 += ks0 + 2u;
    TFR(13) TFR(15) TFR(26) TFR(6)
    x0 += ks0; x1 += ks1 + 3u;
    TFR(17) TFR(29) TFR(16) TFR(24)
    x0 += ks1; x1 += ks2 + 4u;
    TFR(13) TFR(15) TFR(26) TFR(6)
    x0 += ks2; x1 += ks0 + 5u;
#undef TFR
    unsigned bits = x0 ^ x1;
    mask[i] = (bits & 0x80000000u) ? 0.0f : 2.0f;
}

// Pass 1: read edges ONCE, bin into 32 node-range buckets in LDS, append each
// segment to the graph's global bucket region with coalesced ~1KB runs.
__global__ __launch_bounds__(256) void part_kernel(const int* __restrict__ ei,
                                                   const int* __restrict__ flag,
                                                   int* __restrict__ gcur,
                                                   unsigned* __restrict__ gbucket) {
    int b = blockIdx.x & 7;                       // graph (XCD-local)
    int chunk = blockIdx.x >> 3;                  // 0..39
    int e0 = chunk * P1E, e1 = e0 + P1E;
    __shared__ int bcnt[RNG];
    __shared__ unsigned bbuf[RNG][P1CAP];
    for (int i = threadIdx.x; i < RNG; i += 256) bcnt[i] = 0;
    __syncthreads();
    int is64 = *flag;
    size_t base = (size_t)b * 2 * NE;
    for (int e = e0 + threadIdx.x; e < e1; e += 256) {
        int row = load_edge_nt(ei, base + e, is64);
        int col = load_edge_nt(ei, base + NE + e, is64);
        int bk = col / RS;                        // magic-mul division
        unsigned pk = ((unsigned)col << 14) | (unsigned)row;
        int p = atomicAdd(&bcnt[bk], 1);
        if (p < P1CAP) bbuf[bk][p] = pk;
        else {                                    // statistically never
            int gp = atomicAdd(&gcur[b * RNG + bk], 1);
            if (gp < BCAP) gbucket[(size_t)(b * RNG + bk) * BCAP + gp] = pk;
        }
    }
    __syncthreads();
    int wave = threadIdx.x >> 6, lane = threadIdx.x & 63;
    for (int bk = wave; bk < RNG; bk += 4) {
        int len = bcnt[bk]; if (len > P1CAP) len = P1CAP;
        int gb = 0;
        if (lane == 0) gb = atomicAdd(&gcur[b * RNG + bk], len);
        gb = __shfl(gb, 0);
        unsigned* dst = gbucket + (size_t)(b * RNG + bk) * BCAP;
        for (int i = lane; i < len; i += 64)
            if (gb + i < BCAP) dst[gb + i] = bbuf[bk][i];
    }
}

// Pass 2: one block per (graph,range). Read bucket (~10K edges, L2-hot),
// LDS hist -> block scan -> LDS scatter -> coalesced csr copy-out.
// csr entries are PRE-SCALED BYTE OFFSETS (row*256).
__global__ __launch_bounds__(512) void build_kernel(const unsigned* __restrict__ gbucket,
                                                    const int* __restrict__ gcur,
                                                    int* __restrict__ csr,
                                                    int* __restrict__ deg,
                                                    int* __restrict__ offs) {
    int b = blockIdx.x & 7;
    int r = blockIdx.x >> 3;                      // 0..31
    int n0 = r * RS;
    int nloc = (NN - n0 < RS) ? (NN - n0) : RS;
    __shared__ int cnt[512];
    __shared__ int cur[RS];
    __shared__ int buf[BCAP];
    int gidx = b * RNG + r;
    int K = gcur[gidx]; if (K > BCAP) K = BCAP;
    const unsigned* src = gbucket + (size_t)gidx * BCAP;
    int t = threadIdx.x;
    cnt[t] = 0;
    __syncthreads();
    for (int i = t; i < K; i += 512)
        atomicAdd(&cnt[(src[i] >> 14) - n0], 1);
    __syncthreads();
    int v = cnt[t];
    __syncthreads();
    // Hillis-Steele inclusive scan over 512
    int x = v;
    cnt[t] = x;
    __syncthreads();
    for (int off = 1; off < 512; off <<= 1) {
        int add = (t >= off) ? cnt[t - off] : 0;
        __syncthreads();
        x += add;
        cnt[t] = x;
        __syncthreads();
    }
    int excl = x - v;
    if (t < nloc) {
        deg[b * NN + n0 + t] = v;
        offs[b * NN + n0 + t] = gidx * BCAP + excl;   // absolute into csr
        cur[t] = excl;
    }
    __syncthreads();
    for (int i = t; i < K; i += 512) {
        unsigned pk = src[i];
        int p = atomicAdd(&cur[(pk >> 14) - n0], 1);
        buf[p] = (int)((pk & 16383u) << 8);           // row*256 byte offset
    }
    __syncthreads();
    int* dstc = csr + (size_t)gidx * BCAP;
    for (int i = t; i < K; i += 512) dstc[i] = buf[i];   // coalesced
}

__global__ __launch_bounds__(256) void dinv_kernel(const int* __restrict__ deg,
                                                   float* __restrict__ dinv) {
    int i = blockIdx.x * 256 + threadIdx.x;
    if (i >= NB * NN) return;
    dinv[i] = 1.0f / sqrtf((float)(deg[i] + 1));  // +1 self-loop
}

// y = bf16[(X @ W) * dinv[row]] via fp16 MFMA (no fp32 MFMA on CDNA4; fp16
// input rounding adds ~3e-4 RMS/layer, bf16 would be 4x worse).
// Block = 4 waves x 16 rows. W^T staged once per block into LDS fp16
// [col][136] (272B stride: 2-way bank aliasing = free; 16B-aligned b128
// reads). K-association: A and B both use k = kk*32 + 8*(lane>>4) + j —
// any consistent per-lane k-map gives the correct dot product.
// C/D mapping (HW-verified): col = lane&15, row = (lane>>4)*4 + reg.
__global__ __launch_bounds__(256) void gemm_mfma(const float* __restrict__ X,
                                                 const float* __restrict__ Wm,
                                                 const float* __restrict__ dinv,
                                                 unsigned short* __restrict__ y) {
    __shared__ _Float16 WT[128][136];
    int b = blockIdx.x & 7;
    int row0 = (blockIdx.x >> 3) * 64;
    int t = threadIdx.x;
    for (int e = t; e < 16384; e += 256) {        // stage W^T (fp32->fp16)
        int k = e >> 7, c = e & 127;
        WT[c][k] = (_Float16)Wm[e];
    }
    __syncthreads();

    int lane = t & 63;
    int wrow = row0 + (t >> 6) * 16;              // this wave's 16 output rows
    int r = lane & 15;                            // A-row / B-col / D-col
    int g = lane >> 4;                            // k-group
    const float* Xb = X + (size_t)b * NN * NF;
    int grow = wrow + r;

    f32x4 acc[8] = {};
#pragma unroll
    for (int kk = 0; kk < 4; ++kk) {
        half8 a;
        if (grow < NN) {
            const float* px = Xb + (size_t)grow * NF + kk * 32 + g * 8;
            float4 x0 = *(const float4*)px;
            float4 x1 = *(const float4*)(px + 4);
            a[0] = (_Float16)x0.x; a[1] = (_Float16)x0.y;
            a[2] = (_Float16)x0.z; a[3] = (_Float16)x0.w;
            a[4] = (_Float16)x1.x; a[5] = (_Float16)x1.y;
            a[6] = (_Float16)x1.z; a[7] = (_Float16)x1.w;
        } else {
            a = (half8)(_Float16)0.0f;
        }
#pragma unroll
        for (int c = 0; c < 8; ++c) {
            half8 bf = *(const half8*)&WT[c * 16 + r][kk * 32 + g * 8];
            acc[c] = __builtin_amdgcn_mfma_f32_16x16x32_f16(a, bf, acc[c], 0, 0, 0);
        }
    }

    // epilogue: row = wrow + g*4 + i, col = c*16 + r; scale by dinv, store bf16
#pragma unroll
    for (int i = 0; i < 4; ++i) {
        int orow = wrow + g * 4 + i;
        if (orow >= NN) continue;
        float d = dinv[b * NN + orow];
        unsigned short* yp = y + ((size_t)b * NN + orow) * NH + r;
#pragma unroll
        for (int c = 0; c < 8; ++c)
            yp[c * 16] = f2bf(acc[c][i] * d);
    }
}

// Gather-reduce, quarter-wave form (r12-r14: L2-MLP bound; gain tracks bytes
// per outstanding load). Each edge-row (256B) read by a QUARTER wave (16
// lanes x dwordx4); quarters process 4 DIFFERENT edges -> one load = 4 edges
// = 1024B in flight. 2 node-streams x 4 edges = 8 edges per loop body.
template<int LAYER>
__global__ __launch_bounds__(256) void aggregate_full(const unsigned short* __restrict__ y,
                                                      const int* __restrict__ offs,
                                                      const int* __restrict__ deg,
                                                      const int* __restrict__ csr,
                                                      const float* __restrict__ dinv,
                                                      const float* __restrict__ bias,
                                                      const float* __restrict__ mask,
                                                      float* __restrict__ out) {
    int b = blockIdx.x & 7;
    int w = threadIdx.x >> 6;
    int idx = (blockIdx.x >> 3) * 4 + w;     // [0, 5000)
    int n0 = idx, n1 = idx + 5000;
    int lane = threadIdx.x & 63;
    int q = lane >> 4;                       // quarter: which edge of a group of 4
    unsigned q16 = (unsigned)(lane & 15) * 16u;     // byte offset of feat octet
    const char* ybc = (const char*)(y + (size_t)b * NN * NH);   // wave-uniform base

    float a0[8] = {0.f,0.f,0.f,0.f,0.f,0.f,0.f,0.f};
    float a1[8] = {0.f,0.f,0.f,0.f,0.f,0.f,0.f,0.f};
    if (q == 0) {   // self-loop, counted once
        uint4 s0 = *(const uint4*)(ybc + (unsigned)n0 * 256u + q16);
        uint4 s1 = *(const uint4*)(ybc + (unsigned)n1 * 256u + q16);
        bf8_add(a0, s0);
        bf8_add(a1, s1);
    }

    const int* ob = offs + b * NN;
    const int* db = deg + b * NN;
    int ba = ob[n0], o1a = ba + db[n0];
    int bb = ob[n1], o1b = bb + db[n1];

#define PROCQ(r_, j_, acc_) { \
    unsigned o = (unsigned)__shfl((r_), (j_) + q); \
    uint4 u = *(const uint4*)(ybc + o + q16); \
    bf8_add(acc_, u); \
}
#define PROCT(r_, j_, rem_, acc_) { \
    unsigned o = (unsigned)__shfl((r_), (j_) + (q < (rem_) ? q : 0)); \
    uint4 u = *(const uint4*)(ybc + o + q16); \
    if (q < (rem_)) bf8_add(acc_, u); \
}

    while (ba < o1a || bb < o1b) {
        int ma = o1a - ba; ma = ma < 0 ? 0 : (ma > 64 ? 64 : ma);
        int mb = o1b - bb; mb = mb < 0 ? 0 : (mb > 64 ? 64 : mb);
        int ra = (lane < ma) ? csr[ba + lane] : 0;   // byte offsets
        int rb = (lane < mb) ? csr[bb + lane] : 0;
        int mmin = ma < mb ? ma : mb;
        int jj = 0;
#pragma unroll 2
        for (; jj + 3 < mmin; jj += 4) {             // 8 edges in flight
            PROCQ(ra, jj, a0)
            PROCQ(rb, jj, a1)
        }
        int ja = jj, jb = jj;
#pragma unroll 2
        for (; ja + 3 < ma; ja += 4) PROCQ(ra, ja, a0)
        if (ja < ma) PROCT(ra, ja, ma - ja, a0)
#pragma unroll 2
        for (; jb + 3 < mb; jb += 4) PROCQ(rb, jb, a1)
        if (jb < mb) PROCT(rb, jb, mb - jb, a1)
        ba += 64; bb += 64;
    }
#undef PROCQ
#undef PROCT

    // merge the 4 edge-quarters (lanes with equal lane&15 hold same feats)
#pragma unroll
    for (int i = 0; i < 8; ++i) {
        a0[i] += __shfl_xor(a0[i], 16);
        a0[i] += __shfl_xor(a0[i], 32);
        a1[i] += __shfl_xor(a1[i], 16);
        a1[i] += __shfl_xor(a1[i], 32);
    }

    // quarter 0 writes n0, quarter 1 writes n1 (16 lanes x 32B contiguous)
    if (q < 2) {
        int n = q ? n1 : n0;
        float av[8];
#pragma unroll
        for (int i = 0; i < 8; ++i) av[i] = q ? a1[i] : a0[i];
        float d = dinv[b * NN + n];
        unsigned f0 = (lane & 15) * 8;           // first feature of octet
        float4 bi0 = *(const float4*)(bias + f0);
        float4 bi1 = *(const float4*)(bias + f0 + 4);
        float4 o0, o1;
        o0.x = fmaf(d, av[0], bi0.x);
        o0.y = fmaf(d, av[1], bi0.y);
        o0.z = fmaf(d, av[2], bi0.z);
        o0.w = fmaf(d, av[3], bi0.w);
        o1.x = fmaf(d, av[4], bi1.x);
        o1.y = fmaf(d, av[5], bi1.y);
        o1.z = fmaf(d, av[6], bi1.z);
        o1.w = fmaf(d, av[7], bi1.w);
        if (LAYER == 1) {
            float4 m0 = *(const float4*)(mask + (size_t)n * NH + f0);
            float4 m1 = *(const float4*)(mask + (size_t)n * NH + f0 + 4);
            o0.x = fmaxf(o0.x, 0.f) * m0.x;
            o0.y = fmaxf(o0.y, 0.f) * m0.y;
            o0.z = fmaxf(o0.z, 0.f) * m0.z;
            o0.w = fmaxf(o0.w, 0.f) * m0.w;
            o1.x = fmaxf(o1.x, 0.f) * m1.x;
            o1.y = fmaxf(o1.y, 0.f) * m1.y;
            o1.z = fmaxf(o1.z, 0.f) * m1.z;
            o1.w = fmaxf(o1.w, 0.f) * m1.w;
        }
        float* op = out + ((size_t)b * NN + n) * NH + f0;
        *(float4*)op = o0;
        *(float4*)(op + 4) = o1;
    }
}

extern "C" void kernel_launch(void* const* d_in, const int* in_sizes, int n_in,
                              void* d_out, int out_size, void* d_ws, size_t ws_size,
                              hipStream_t stream) {
    const float* xs = (const float*)d_in[0];
    const int*   ei = (const int*)d_in[1];
    const float* W1 = (const float*)d_in[2];
    const float* b1 = (const float*)d_in[3];
    const float* W2 = (const float*)d_in[4];
    const float* b2 = (const float*)d_in[5];
    float* out = (float*)d_out;

    float* ws        = (float*)d_ws;
    float* dinv      = ws;
    int*   deg       = (int*)(ws + 80000);
    int*   flag      = (int*)(ws + 160000);
    float* mask      = ws + 160016;
    int*   offs      = (int*)(ws + 1440016);
    int*   gcur      = (int*)(ws + 1520016);
    unsigned* gbucket= (unsigned*)(ws + 1520272);
    int*   csr       = (int*)(ws + 4666000);
    unsigned short* y= (unsigned short*)(ws + 7811728);

    hipMemsetAsync(gcur, 0, NB * RNG * sizeof(int), stream);
    detect_kernel<<<1, 256, 0, stream>>>(ei, flag);
    mask_kernel<<<(NN * NH + 255) / 256, 256, 0, stream>>>(mask);
    part_kernel<<<8 * (NE / P1E), 256, 0, stream>>>(ei, flag, gcur, gbucket);
    build_kernel<<<NB * RNG, 512, 0, stream>>>(gbucket, gcur, csr, deg, offs);
    dinv_kernel<<<(NB * NN + 255) / 256, 256, 0, stream>>>(deg, dinv);

    dim3 gemm_grid(8 * ((NN + 63) / 64));   // blockIdx&7 = graph (XCD-local)
    dim3 agg_grid(NB * (5000 / 4));         // 10000 blocks, 4 waves x 2 nodes each

    // Layer 1: h -> d_out
    gemm_mfma<<<gemm_grid, 256, 0, stream>>>(xs, W1, dinv, y);
    aggregate_full<1><<<agg_grid, 256, 0, stream>>>(y, offs, deg, csr, dinv, b1, mask, out);

    // Layer 2: reads h from d_out into y, then overwrites d_out
    gemm_mfma<<<gemm_grid, 256, 0, stream>>>(out, W2, dinv, y);
    aggregate_full<2><<<agg_grid, 256, 0, stream>>>(y, offs, deg, csr, dinv, b2, nullptr, out);
}